// Round 6
// baseline (469.834 us; speedup 1.0000x reference)
//
#include <hip/hip_runtime.h>
#include <cstddef>
#include <math.h>

#define S_LEN  2048
#define HID_C  1024
#define NHEADS 16
#define HDIM   64

typedef __attribute__((ext_vector_type(8))) short bf16x8;
typedef __attribute__((ext_vector_type(4))) float f32x4;
typedef unsigned short ushort_t;

#define LOG2E 1.44269504088896f

// cheap round-to-nearest fp32 -> bf16 (ties-up; same 1/2-ulp bound as RNE)
__device__ __forceinline__ unsigned short f32_to_bf16_rn(float f) {
    unsigned int u = __float_as_uint(f);
    return (unsigned short)((u + 0x8000u) >> 16);
}

// ---------------------------------------------------------------------------
// mask (int 0/1) -> additive f32 bias (0 / -1e30)
// ---------------------------------------------------------------------------
__global__ void mask_to_bias(const int* __restrict__ m, float* __restrict__ mb, int n) {
    int i = blockIdx.x * 256 + threadIdx.x;
    if (i < n) mb[i] = m[i] ? 0.f : -1e30f;
}

// ---------------------------------------------------------------------------
// MFMA GEMM, split-A: out[m,n] = (sum_k X[m,k]*W[n,k] + bias) * oscale
//   A = X split hi+lo bf16, B = W rounded bf16. acc += xh*wh + xl*wh.
// OMODE 0: fp32 out, col bias. OMODE 1: bf16 out, col bias.
// OMODE 2: bf16 out, ROW bias (swapped V^T GEMM).
// ASPLIT 0: fp32 source. ASPLIT 1: pre-split bf16 hi/lo source.
// 128x128 tile, BK=32, 4 waves (2x2), 64x64/wave. LDS rows 40 shorts.
// ---------------------------------------------------------------------------
#define BM 128
#define BN 128
#define BKg 32
#define LDKg 40

template <int OMODE, int ASPLIT>
__global__ __launch_bounds__(256) void gemm_xwt_bias_mfma(
    const float* __restrict__ Xf,
    const ushort_t* __restrict__ Xhi, const ushort_t* __restrict__ Xlo,
    const float* __restrict__ W, const float* __restrict__ bias,
    float* __restrict__ outF, ushort_t* __restrict__ outB,
    int M, int N, int K, float oscale)
{
    __shared__ __align__(16) short Ah[BM * LDKg];
    __shared__ __align__(16) short Al[BM * LDKg];
    __shared__ __align__(16) short Bh[BM * LDKg];

    const int tid  = threadIdx.x;
    const int lane = tid & 63;
    const int wave = tid >> 6;
    const int bm = blockIdx.y * BM;
    const int bn = blockIdx.x * BN;
    const int wm = (wave >> 1) * 64;
    const int wn = (wave & 1) * 64;

    const int sr = tid >> 1;
    const int sc = (tid & 1) * 16;

    const float* Wp = W + (size_t)(bn + sr) * K + sc;

    f32x4 acc[4][4];
#pragma unroll
    for (int i = 0; i < 4; ++i)
#pragma unroll
        for (int j = 0; j < 4; ++j)
#pragma unroll
            for (int r = 0; r < 4; ++r) acc[i][j][r] = 0.f;

    const int fr = lane & 15;
    const int kb = (lane >> 4) * 8;

    for (int k0 = 0; k0 < K; k0 += BKg) {
        short xh[16], xl[16], wh[16];
        if (ASPLIT == 0) {
            const float* Xp = Xf + (size_t)(bm + sr) * K + sc + k0;
            float xv[16];
#pragma unroll
            for (int q = 0; q < 4; ++q) {
                float4 a = *reinterpret_cast<const float4*>(Xp + q * 4);
                xv[q*4+0]=a.x; xv[q*4+1]=a.y; xv[q*4+2]=a.z; xv[q*4+3]=a.w;
            }
#pragma unroll
            for (int j = 0; j < 16; ++j) {
                unsigned int u = __float_as_uint(xv[j]);
                xh[j] = (short)(u >> 16);                       // trunc hi
                float res = xv[j] - __uint_as_float(u & 0xFFFF0000u);
                xl[j] = (short)f32_to_bf16_rn(res);
            }
        } else {
            const ushort_t* hp = Xhi + (size_t)(bm + sr) * K + sc + k0;
            const ushort_t* lp = Xlo + (size_t)(bm + sr) * K + sc + k0;
            *reinterpret_cast<bf16x8*>(&xh[0]) = *reinterpret_cast<const bf16x8*>(hp);
            *reinterpret_cast<bf16x8*>(&xh[8]) = *reinterpret_cast<const bf16x8*>(hp + 8);
            *reinterpret_cast<bf16x8*>(&xl[0]) = *reinterpret_cast<const bf16x8*>(lp);
            *reinterpret_cast<bf16x8*>(&xl[8]) = *reinterpret_cast<const bf16x8*>(lp + 8);
        }
        {
            float wv[16];
#pragma unroll
            for (int q = 0; q < 4; ++q) {
                float4 b = *reinterpret_cast<const float4*>(Wp + k0 + q * 4);
                wv[q*4+0]=b.x; wv[q*4+1]=b.y; wv[q*4+2]=b.z; wv[q*4+3]=b.w;
            }
#pragma unroll
            for (int j = 0; j < 16; ++j) wh[j] = (short)f32_to_bf16_rn(wv[j]);
        }

        __syncthreads();
        const int wbase = sr * LDKg + sc;
        *reinterpret_cast<bf16x8*>(&Ah[wbase])     = *reinterpret_cast<bf16x8*>(&xh[0]);
        *reinterpret_cast<bf16x8*>(&Ah[wbase + 8]) = *reinterpret_cast<bf16x8*>(&xh[8]);
        *reinterpret_cast<bf16x8*>(&Al[wbase])     = *reinterpret_cast<bf16x8*>(&xl[0]);
        *reinterpret_cast<bf16x8*>(&Al[wbase + 8]) = *reinterpret_cast<bf16x8*>(&xl[8]);
        *reinterpret_cast<bf16x8*>(&Bh[wbase])     = *reinterpret_cast<bf16x8*>(&wh[0]);
        *reinterpret_cast<bf16x8*>(&Bh[wbase + 8]) = *reinterpret_cast<bf16x8*>(&wh[8]);
        __syncthreads();

        bf16x8 fah[4], fal[4], fbh[4];
#pragma unroll
        for (int mi = 0; mi < 4; ++mi) {
            const int ra = (wm + mi * 16 + fr) * LDKg + kb;
            fah[mi] = *reinterpret_cast<const bf16x8*>(&Ah[ra]);
            fal[mi] = *reinterpret_cast<const bf16x8*>(&Al[ra]);
        }
#pragma unroll
        for (int ni = 0; ni < 4; ++ni) {
            const int rb = (wn + ni * 16 + fr) * LDKg + kb;
            fbh[ni] = *reinterpret_cast<const bf16x8*>(&Bh[rb]);
        }

        __builtin_amdgcn_s_setprio(1);
#pragma unroll
        for (int mi = 0; mi < 4; ++mi)
#pragma unroll
            for (int ni = 0; ni < 4; ++ni) {
                acc[mi][ni] = __builtin_amdgcn_mfma_f32_16x16x32_bf16(
                    fah[mi], fbh[ni], acc[mi][ni], 0, 0, 0);
                acc[mi][ni] = __builtin_amdgcn_mfma_f32_16x16x32_bf16(
                    fal[mi], fbh[ni], acc[mi][ni], 0, 0, 0);
            }
        __builtin_amdgcn_s_setprio(0);
    }

    const int fq = lane >> 4;
    if (OMODE == 2) {
#pragma unroll
        for (int mi = 0; mi < 4; ++mi) {
#pragma unroll
            for (int r = 0; r < 4; ++r) {
                const int row = bm + wm + mi * 16 + fq * 4 + r;
                const float bvr = bias[row];
#pragma unroll
                for (int ni = 0; ni < 4; ++ni) {
                    const int col = bn + wn + ni * 16 + fr;
                    outB[(size_t)row * N + col] =
                        f32_to_bf16_rn((acc[mi][ni][r] + bvr) * oscale);
                }
            }
        }
    } else {
        float bv[4];
#pragma unroll
        for (int ni = 0; ni < 4; ++ni) bv[ni] = bias[bn + wn + ni * 16 + fr];
#pragma unroll
        for (int mi = 0; mi < 4; ++mi)
#pragma unroll
            for (int ni = 0; ni < 4; ++ni) {
                const size_t rowb = (size_t)(bm + wm + mi * 16 + fq * 4);
                const int col = bn + wn + ni * 16 + fr;
#pragma unroll
                for (int r = 0; r < 4; ++r) {
                    float v = (acc[mi][ni][r] + bv[ni]) * oscale;
                    if (OMODE == 0) outF[(rowb + r) * N + col] = v;
                    else            outB[(rowb + r) * N + col] = f32_to_bf16_rn(v);
                }
            }
    }
}

// ---------------------------------------------------------------------------
// Flash attention, bf16 MFMA, T14 register-prefetch of K/V(t+1).
// One block = (b, h, 128-row Q tile); 4 waves, wave w owns 32 q-rows.
// Q comes pre-scaled by 0.125*log2e; mask comes as additive f32 bias.
// K LDS [k][72]; V pre-transposed in global -> V LDS [d][72] plain writes.
// Softmax exp2-domain, T13 defer-max. Output pre-split hi/lo bf16.
// ---------------------------------------------------------------------------
#define QBLK 128
#define KVB  64
#define LDA  72

__global__ __launch_bounds__(256) void flash_attn_bf16(
    const ushort_t* __restrict__ Qb, const ushort_t* __restrict__ Kb,
    const ushort_t* __restrict__ Vtg, const float* __restrict__ maskb,
    ushort_t* __restrict__ Xhi, ushort_t* __restrict__ Xlo)
{
    __shared__ __align__(16) ushort_t Ks[KVB * LDA];
    __shared__ __align__(16) ushort_t Vt[HDIM * LDA];
    __shared__ __align__(16) ushort_t Ps[QBLK * LDA];

    const int b  = blockIdx.y >> 4;
    const int h  = blockIdx.y & 15;
    const int q0 = blockIdx.x * QBLK;
    const int tid  = threadIdx.x;
    const int lane = tid & 63;
    const int w    = tid >> 6;
    const int fr = lane & 15;
    const int fq = lane >> 4;

    const size_t bS = (size_t)b * S_LEN;
    const int hc = h * HDIM;

    // Q fragments in registers (pre-scaled)
    bf16x8 qf[2][2];
#pragma unroll
    for (int mt = 0; mt < 2; ++mt)
#pragma unroll
        for (int c = 0; c < 2; ++c)
            qf[mt][c] = *reinterpret_cast<const bf16x8*>(
                &Qb[(bS + q0 + w * 32 + mt * 16 + fr) * HID_C + hc + c * 32 + fq * 8]);

    f32x4 OV[2][4];
    float m_[8], l_[8];
#pragma unroll
    for (int mt = 0; mt < 2; ++mt)
#pragma unroll
        for (int dt = 0; dt < 4; ++dt)
#pragma unroll
            for (int r = 0; r < 4; ++r) OV[mt][dt][r] = 0.f;
#pragma unroll
    for (int i = 0; i < 8; ++i) { m_[i] = -1e30f; l_[i] = 0.f; }

    const int sr  = tid >> 2;
    const int seg = tid & 3;
    const ushort_t* kbase = &Kb[(bS + sr) * HID_C + hc + seg * 16];
    const ushort_t* vbase = &Vtg[(size_t)(hc + sr) * (4 * S_LEN) + bS + seg * 16];

    // ---- prologue: stage tile t=0 ----
    {
        bf16x8 kv0 = *reinterpret_cast<const bf16x8*>(kbase);
        bf16x8 kv1 = *reinterpret_cast<const bf16x8*>(kbase + 8);
        bf16x8 vv0 = *reinterpret_cast<const bf16x8*>(vbase);
        bf16x8 vv1 = *reinterpret_cast<const bf16x8*>(vbase + 8);
        *reinterpret_cast<bf16x8*>(&Ks[sr * LDA + seg * 16])     = kv0;
        *reinterpret_cast<bf16x8*>(&Ks[sr * LDA + seg * 16 + 8]) = kv1;
        *reinterpret_cast<bf16x8*>(&Vt[sr * LDA + seg * 16])     = vv0;
        *reinterpret_cast<bf16x8*>(&Vt[sr * LDA + seg * 16 + 8]) = vv1;
        __syncthreads();
    }

    for (int t = 0; t < S_LEN; t += KVB) {
        // ---- mask bias loads (early issue) ----
        float mb[4];
#pragma unroll
        for (int nt = 0; nt < 4; ++nt) mb[nt] = maskb[bS + t + nt * 16 + fr];

        // ---- QK^T ----
        f32x4 S[2][4];
#pragma unroll
        for (int mt = 0; mt < 2; ++mt)
#pragma unroll
            for (int nt = 0; nt < 4; ++nt)
#pragma unroll
                for (int r = 0; r < 4; ++r) S[mt][nt][r] = 0.f;

        __builtin_amdgcn_s_setprio(1);
#pragma unroll
        for (int nt = 0; nt < 4; ++nt)
#pragma unroll
            for (int c = 0; c < 2; ++c) {
                bf16x8 kf = *reinterpret_cast<const bf16x8*>(
                    &Ks[(nt * 16 + fr) * LDA + c * 32 + fq * 8]);
#pragma unroll
                for (int mt = 0; mt < 2; ++mt)
                    S[mt][nt] = __builtin_amdgcn_mfma_f32_16x16x32_bf16(
                        qf[mt][c], kf, S[mt][nt], 0, 0, 0);
            }
        __builtin_amdgcn_s_setprio(0);

        // ---- T14: issue next-tile K/V loads; drain under softmax+PV ----
        const bool more = (t + KVB < S_LEN);
        bf16x8 kv0n, kv1n, vv0n, vv1n;
        if (more) {
            const ushort_t* kp = kbase + (size_t)(t + KVB) * HID_C;
            const ushort_t* vp = vbase + (t + KVB);
            kv0n = *reinterpret_cast<const bf16x8*>(kp);
            kv1n = *reinterpret_cast<const bf16x8*>(kp + 8);
            vv0n = *reinterpret_cast<const bf16x8*>(vp);
            vv1n = *reinterpret_cast<const bf16x8*>(vp + 8);
        }

        // ---- mask add ----
#pragma unroll
        for (int mt = 0; mt < 2; ++mt)
#pragma unroll
            for (int nt = 0; nt < 4; ++nt)
#pragma unroll
                for (int r = 0; r < 4; ++r) S[mt][nt][r] += mb[nt];

        // ---- row max + defer-max ----
        float mx[2][4];
        int okl = 1;
#pragma unroll
        for (int mt = 0; mt < 2; ++mt)
#pragma unroll
            for (int r = 0; r < 4; ++r) {
                float v = fmaxf(fmaxf(S[mt][0][r], S[mt][1][r]),
                                fmaxf(S[mt][2][r], S[mt][3][r]));
                v = fmaxf(v, __shfl_xor(v, 1));
                v = fmaxf(v, __shfl_xor(v, 2));
                v = fmaxf(v, __shfl_xor(v, 4));
                v = fmaxf(v, __shfl_xor(v, 8));
                mx[mt][r] = v;
                okl &= (v <= m_[mt * 4 + r] + 8.f);
            }
        if (!__all(okl)) {
#pragma unroll
            for (int mt = 0; mt < 2; ++mt)
#pragma unroll
                for (int r = 0; r < 4; ++r) {
                    const int qi = mt * 4 + r;
                    float mn = fmaxf(m_[qi], mx[mt][r]);
                    float corr = exp2f(m_[qi] - mn);
                    m_[qi] = mn;
                    l_[qi] *= corr;
#pragma unroll
                    for (int dt = 0; dt < 4; ++dt) OV[mt][dt][r] *= corr;
                }
        }

        // ---- P = exp2(S - m), row-sum, stage P (wave-private) ----
#pragma unroll
        for (int mt = 0; mt < 2; ++mt)
#pragma unroll
            for (int r = 0; r < 4; ++r) {
                const int qi = mt * 4 + r;
                float ls = 0.f;
#pragma unroll
                for (int nt = 0; nt < 4; ++nt) {
                    float p = exp2f(S[mt][nt][r] - m_[qi]);
                    Ps[(w * 32 + mt * 16 + fq * 4 + r) * LDA + nt * 16 + fr] =
                        f32_to_bf16_rn(p);
                    ls += p;
                }
                ls += __shfl_xor(ls, 1);
                ls += __shfl_xor(ls, 2);
                ls += __shfl_xor(ls, 4);
                ls += __shfl_xor(ls, 8);
                l_[qi] += ls;
            }

        // ---- PV ----
        bf16x8 pf[2][2];
#pragma unroll
        for (int mt = 0; mt < 2; ++mt)
#pragma unroll
            for (int c = 0; c < 2; ++c)
                pf[mt][c] = *reinterpret_cast<const bf16x8*>(
                    &Ps[(w * 32 + mt * 16 + fr) * LDA + c * 32 + fq * 8]);

        __builtin_amdgcn_s_setprio(1);
#pragma unroll
        for (int dt = 0; dt < 4; ++dt)
#pragma unroll
            for (int c = 0; c < 2; ++c) {
                bf16x8 vf = *reinterpret_cast<const bf16x8*>(
                    &Vt[(dt * 16 + fr) * LDA + c * 32 + fq * 8]);
#pragma unroll
                for (int mt = 0; mt < 2; ++mt)
                    OV[mt][dt] = __builtin_amdgcn_mfma_f32_16x16x32_bf16(
                        pf[mt][c], vf, OV[mt][dt], 0, 0, 0);
            }
        __builtin_amdgcn_s_setprio(0);

        // ---- stage next tile ----
        __syncthreads();
        if (more) {
            *reinterpret_cast<bf16x8*>(&Ks[sr * LDA + seg * 16])     = kv0n;
            *reinterpret_cast<bf16x8*>(&Ks[sr * LDA + seg * 16 + 8]) = kv1n;
            *reinterpret_cast<bf16x8*>(&Vt[sr * LDA + seg * 16])     = vv0n;
            *reinterpret_cast<bf16x8*>(&Vt[sr * LDA + seg * 16 + 8]) = vv1n;
            __syncthreads();
        }
    }

    // ---- epilogue: x = OV/l, pre-split hi/lo bf16 ----
#pragma unroll
    for (int mt = 0; mt < 2; ++mt)
#pragma unroll
        for (int r = 0; r < 4; ++r) {
            const float inv = 1.f / l_[mt * 4 + r];
            const size_t row = bS + q0 + w * 32 + mt * 16 + fq * 4 + r;
#pragma unroll
            for (int dt = 0; dt < 4; ++dt) {
                float v = OV[mt][dt][r] * inv;
                unsigned int u = __float_as_uint(v);
                unsigned short hi = (unsigned short)(u >> 16);
                float res = v - __uint_as_float(u & 0xFFFF0000u);
                Xhi[row * HID_C + hc + dt * 16 + fr] = hi;
                Xlo[row * HID_C + hc + dt * 16 + fr] = f32_to_bf16_rn(res);
            }
        }
}

// ---------------------------------------------------------------------------
extern "C" void kernel_launch(void* const* d_in, const int* in_sizes, int n_in,
                              void* d_out, int out_size, void* d_ws, size_t ws_size,
                              hipStream_t stream) {
    const float* query = (const float*)d_in[0];
    const float* key   = (const float*)d_in[1];
    const float* value = (const float*)d_in[2];
    const int*   mask  = (const int*)d_in[3];
    const float* Wq = (const float*)d_in[4];
    const float* bq = (const float*)d_in[5];
    const float* Wk = (const float*)d_in[6];
    const float* bk = (const float*)d_in[7];
    const float* Wv = (const float*)d_in[8];
    const float* bv = (const float*)d_in[9];
    const float* Wo = (const float*)d_in[10];
    const float* bo = (const float*)d_in[11];
    float* out = (float*)d_out;

    const int B = 4, M = B * S_LEN;          // 8192
    const size_t seg = (size_t)M * HID_C;

    ushort_t* Qb  = (ushort_t*)d_ws;         // 16MB each
    ushort_t* Kb  = Qb + seg;
    ushort_t* Vtg = Kb + seg;                // V^T: [1024 feat][8192 tok]
    ushort_t* Xhi = Vtg + seg;
    ushort_t* Xlo = Xhi + seg;
    float*    Mb  = (float*)(Xlo + seg);     // mask bias: 32KB (total ~80MB)

    mask_to_bias<<<dim3(M / 256), 256, 0, stream>>>(mask, Mb, M);

    const float SC2 = 0.125f * LOG2E;
    dim3 gg(HID_C / BN, M / BM);             // (8, 64)
    gemm_xwt_bias_mfma<1, 0><<<gg, 256, 0, stream>>>(
        query, nullptr, nullptr, Wq, bq, nullptr, Qb, M, HID_C, HID_C, SC2);
    gemm_xwt_bias_mfma<1, 0><<<gg, 256, 0, stream>>>(
        key,   nullptr, nullptr, Wk, bk, nullptr, Kb, M, HID_C, HID_C, 1.f);
    dim3 gv(M / BN, HID_C / BM);             // (64, 8)
    gemm_xwt_bias_mfma<2, 0><<<gv, 256, 0, stream>>>(
        Wv, nullptr, nullptr, value, bv, nullptr, Vtg, HID_C, M, HID_C, 1.f);

    dim3 ga(S_LEN / QBLK, B * NHEADS);       // (16, 64)
    flash_attn_bf16<<<ga, 256, 0, stream>>>(Qb, Kb, Vtg, Mb, Xhi, Xlo);

    gemm_xwt_bias_mfma<0, 1><<<gg, 256, 0, stream>>>(
        nullptr, Xhi, Xlo, Wo, bo, out, nullptr, M, HID_C, HID_C, 1.f);
}

// Round 7
// 378.639 us; speedup vs baseline: 1.2408x; 1.2408x over previous
//
#include <hip/hip_runtime.h>
#include <cstddef>
#include <math.h>

#define S_LEN  2048
#define HID_C  1024
#define NHEADS 16
#define HDIM   64

typedef __attribute__((ext_vector_type(8))) short bf16x8;
typedef __attribute__((ext_vector_type(4))) float f32x4;
typedef unsigned short ushort_t;

#define LOG2E 1.44269504088896f

// cheap round-to-nearest fp32 -> bf16 (ties-up; same 1/2-ulp bound as RNE)
__device__ __forceinline__ unsigned short f32_to_bf16_rn(float f) {
    unsigned int u = __float_as_uint(f);
    return (unsigned short)((u + 0x8000u) >> 16);
}

// ---------------------------------------------------------------------------
// mask (int 0/1) -> additive f32 bias (0 / -1e30)
// ---------------------------------------------------------------------------
__global__ void mask_to_bias(const int* __restrict__ m, float* __restrict__ mb, int n) {
    int i = blockIdx.x * 256 + threadIdx.x;
    if (i < n) mb[i] = m[i] ? 0.f : -1e30f;
}

// ---------------------------------------------------------------------------
// MFMA GEMM, split-A: out[m,n] = (sum_k X[m,k]*W[n,k] + bias) * oscale
// OMODE 0: fp32 out, col bias. OMODE 1: bf16 out, col bias.
// OMODE 2: bf16 out, ROW bias (swapped V^T GEMM).
// ASPLIT 0: fp32 source. ASPLIT 1: pre-split bf16 hi/lo source.
// 128x128 tile, BK=32, 4 waves (2x2), 64x64/wave. LDS rows 40 shorts.
// (no setprio here: m190 — hurts lockstep GEMM)
// ---------------------------------------------------------------------------
#define BM 128
#define BN 128
#define BKg 32
#define LDKg 40

template <int OMODE, int ASPLIT>
__global__ __launch_bounds__(256) void gemm_xwt_bias_mfma(
    const float* __restrict__ Xf,
    const ushort_t* __restrict__ Xhi, const ushort_t* __restrict__ Xlo,
    const float* __restrict__ W, const float* __restrict__ bias,
    float* __restrict__ outF, ushort_t* __restrict__ outB,
    int M, int N, int K, float oscale)
{
    __shared__ __align__(16) short Ah[BM * LDKg];
    __shared__ __align__(16) short Al[BM * LDKg];
    __shared__ __align__(16) short Bh[BM * LDKg];

    const int tid  = threadIdx.x;
    const int lane = tid & 63;
    const int wave = tid >> 6;
    const int bm = blockIdx.y * BM;
    const int bn = blockIdx.x * BN;
    const int wm = (wave >> 1) * 64;
    const int wn = (wave & 1) * 64;

    const int sr = tid >> 1;
    const int sc = (tid & 1) * 16;

    const float* Wp = W + (size_t)(bn + sr) * K + sc;

    f32x4 acc[4][4];
#pragma unroll
    for (int i = 0; i < 4; ++i)
#pragma unroll
        for (int j = 0; j < 4; ++j)
#pragma unroll
            for (int r = 0; r < 4; ++r) acc[i][j][r] = 0.f;

    const int fr = lane & 15;
    const int kb = (lane >> 4) * 8;

    for (int k0 = 0; k0 < K; k0 += BKg) {
        short xh[16], xl[16], wh[16];
        if (ASPLIT == 0) {
            const float* Xp = Xf + (size_t)(bm + sr) * K + sc + k0;
            float xv[16];
#pragma unroll
            for (int q = 0; q < 4; ++q) {
                float4 a = *reinterpret_cast<const float4*>(Xp + q * 4);
                xv[q*4+0]=a.x; xv[q*4+1]=a.y; xv[q*4+2]=a.z; xv[q*4+3]=a.w;
            }
#pragma unroll
            for (int j = 0; j < 16; ++j) {
                unsigned int u = __float_as_uint(xv[j]);
                xh[j] = (short)(u >> 16);                       // trunc hi
                float res = xv[j] - __uint_as_float(u & 0xFFFF0000u);
                xl[j] = (short)f32_to_bf16_rn(res);
            }
        } else {
            const ushort_t* hp = Xhi + (size_t)(bm + sr) * K + sc + k0;
            const ushort_t* lp = Xlo + (size_t)(bm + sr) * K + sc + k0;
            *reinterpret_cast<bf16x8*>(&xh[0]) = *reinterpret_cast<const bf16x8*>(hp);
            *reinterpret_cast<bf16x8*>(&xh[8]) = *reinterpret_cast<const bf16x8*>(hp + 8);
            *reinterpret_cast<bf16x8*>(&xl[0]) = *reinterpret_cast<const bf16x8*>(lp);
            *reinterpret_cast<bf16x8*>(&xl[8]) = *reinterpret_cast<const bf16x8*>(lp + 8);
        }
        {
            float wv[16];
#pragma unroll
            for (int q = 0; q < 4; ++q) {
                float4 b = *reinterpret_cast<const float4*>(Wp + k0 + q * 4);
                wv[q*4+0]=b.x; wv[q*4+1]=b.y; wv[q*4+2]=b.z; wv[q*4+3]=b.w;
            }
#pragma unroll
            for (int j = 0; j < 16; ++j) wh[j] = (short)f32_to_bf16_rn(wv[j]);
        }

        __syncthreads();
        const int wbase = sr * LDKg + sc;
        *reinterpret_cast<bf16x8*>(&Ah[wbase])     = *reinterpret_cast<bf16x8*>(&xh[0]);
        *reinterpret_cast<bf16x8*>(&Ah[wbase + 8]) = *reinterpret_cast<bf16x8*>(&xh[8]);
        *reinterpret_cast<bf16x8*>(&Al[wbase])     = *reinterpret_cast<bf16x8*>(&xl[0]);
        *reinterpret_cast<bf16x8*>(&Al[wbase + 8]) = *reinterpret_cast<bf16x8*>(&xl[8]);
        *reinterpret_cast<bf16x8*>(&Bh[wbase])     = *reinterpret_cast<bf16x8*>(&wh[0]);
        *reinterpret_cast<bf16x8*>(&Bh[wbase + 8]) = *reinterpret_cast<bf16x8*>(&wh[8]);
        __syncthreads();

        bf16x8 fah[4], fal[4], fbh[4];
#pragma unroll
        for (int mi = 0; mi < 4; ++mi) {
            const int ra = (wm + mi * 16 + fr) * LDKg + kb;
            fah[mi] = *reinterpret_cast<const bf16x8*>(&Ah[ra]);
            fal[mi] = *reinterpret_cast<const bf16x8*>(&Al[ra]);
        }
#pragma unroll
        for (int ni = 0; ni < 4; ++ni) {
            const int rb = (wn + ni * 16 + fr) * LDKg + kb;
            fbh[ni] = *reinterpret_cast<const bf16x8*>(&Bh[rb]);
        }

#pragma unroll
        for (int mi = 0; mi < 4; ++mi)
#pragma unroll
            for (int ni = 0; ni < 4; ++ni) {
                acc[mi][ni] = __builtin_amdgcn_mfma_f32_16x16x32_bf16(
                    fah[mi], fbh[ni], acc[mi][ni], 0, 0, 0);
                acc[mi][ni] = __builtin_amdgcn_mfma_f32_16x16x32_bf16(
                    fal[mi], fbh[ni], acc[mi][ni], 0, 0, 0);
            }
    }

    const int fq = lane >> 4;
    if (OMODE == 2) {
#pragma unroll
        for (int mi = 0; mi < 4; ++mi) {
#pragma unroll
            for (int r = 0; r < 4; ++r) {
                const int row = bm + wm + mi * 16 + fq * 4 + r;
                const float bvr = bias[row];
#pragma unroll
                for (int ni = 0; ni < 4; ++ni) {
                    const int col = bn + wn + ni * 16 + fr;
                    outB[(size_t)row * N + col] =
                        f32_to_bf16_rn((acc[mi][ni][r] + bvr) * oscale);
                }
            }
        }
    } else {
        float bv[4];
#pragma unroll
        for (int ni = 0; ni < 4; ++ni) bv[ni] = bias[bn + wn + ni * 16 + fr];
#pragma unroll
        for (int mi = 0; mi < 4; ++mi)
#pragma unroll
            for (int ni = 0; ni < 4; ++ni) {
                const size_t rowb = (size_t)(bm + wm + mi * 16 + fq * 4);
                const int col = bn + wn + ni * 16 + fr;
#pragma unroll
                for (int r = 0; r < 4; ++r) {
                    float v = (acc[mi][ni][r] + bv[ni]) * oscale;
                    if (OMODE == 0) outF[(rowb + r) * N + col] = v;
                    else            outB[(rowb + r) * N + col] = f32_to_bf16_rn(v);
                }
            }
    }
}

// ---------------------------------------------------------------------------
// Flash attention, bf16 MFMA, SWAPPED QK^T: S = mfma(K, Q) -> C[row=k,col=q],
// so each lane's 16 regs per q-row are lane-local k-slices. Row max/sum are
// in-register + 2 shfl (x16, x32). P staged via packed b64 writes.
// Softmax state (m,l) at q=fr; OV rescale transpose via wave-private LDS
// array only in the (rare) defer-max branch; l transposed once at epilogue.
// Q pre-scaled by 0.125*log2e; mask is additive f32 bias; T14 reg-prefetch.
// ---------------------------------------------------------------------------
#define QBLK 128
#define KVB  64
#define LDA  72

__global__ __launch_bounds__(256) void flash_attn_bf16(
    const ushort_t* __restrict__ Qb, const ushort_t* __restrict__ Kb,
    const ushort_t* __restrict__ Vtg, const float* __restrict__ maskb,
    ushort_t* __restrict__ Xhi, ushort_t* __restrict__ Xlo)
{
    __shared__ __align__(16) ushort_t Ks[KVB * LDA];
    __shared__ __align__(16) ushort_t Vt[HDIM * LDA];
    __shared__ __align__(16) ushort_t Ps[QBLK * LDA];
    __shared__ float XposeA[QBLK];   // per-q corr / 1/l transpose scratch

    const int b  = blockIdx.y >> 4;
    const int h  = blockIdx.y & 15;
    const int q0 = blockIdx.x * QBLK;
    const int tid  = threadIdx.x;
    const int lane = tid & 63;
    const int w    = tid >> 6;
    const int fr = lane & 15;
    const int fq = lane >> 4;

    const size_t bS = (size_t)b * S_LEN;
    const int hc = h * HDIM;

    // Q fragments (pre-scaled): B-operand, col = q = w*32 + mt*16 + fr
    bf16x8 qf[2][2];
#pragma unroll
    for (int mt = 0; mt < 2; ++mt)
#pragma unroll
        for (int c = 0; c < 2; ++c)
            qf[mt][c] = *reinterpret_cast<const bf16x8*>(
                &Qb[(bS + q0 + w * 32 + mt * 16 + fr) * HID_C + hc + c * 32 + fq * 8]);

    f32x4 OV[2][4];
    float m_[2], l_[2];
#pragma unroll
    for (int mt = 0; mt < 2; ++mt) {
        m_[mt] = -1e30f; l_[mt] = 0.f;
#pragma unroll
        for (int dt = 0; dt < 4; ++dt)
#pragma unroll
            for (int r = 0; r < 4; ++r) OV[mt][dt][r] = 0.f;
    }

    const int sr  = tid >> 2;
    const int seg = tid & 3;
    const ushort_t* kbase = &Kb[(bS + sr) * HID_C + hc + seg * 16];
    const ushort_t* vbase = &Vtg[(size_t)(hc + sr) * (4 * S_LEN) + bS + seg * 16];

    // ---- prologue: stage tile t=0 ----
    {
        bf16x8 kv0 = *reinterpret_cast<const bf16x8*>(kbase);
        bf16x8 kv1 = *reinterpret_cast<const bf16x8*>(kbase + 8);
        bf16x8 vv0 = *reinterpret_cast<const bf16x8*>(vbase);
        bf16x8 vv1 = *reinterpret_cast<const bf16x8*>(vbase + 8);
        *reinterpret_cast<bf16x8*>(&Ks[sr * LDA + seg * 16])     = kv0;
        *reinterpret_cast<bf16x8*>(&Ks[sr * LDA + seg * 16 + 8]) = kv1;
        *reinterpret_cast<bf16x8*>(&Vt[sr * LDA + seg * 16])     = vv0;
        *reinterpret_cast<bf16x8*>(&Vt[sr * LDA + seg * 16 + 8]) = vv1;
        __syncthreads();
    }

    for (int t = 0; t < S_LEN; t += KVB) {
        // ---- mask bias (additive), k = t + nt*16 + fq*4 + r ----
        float4 mbv[4];
#pragma unroll
        for (int nt = 0; nt < 4; ++nt)
            mbv[nt] = *reinterpret_cast<const float4*>(&maskb[bS + t + nt * 16 + fq * 4]);

        // ---- QK^T (swapped): S[mt][nt] = K(ntile) x Q(mtile) ----
        f32x4 S[2][4];
#pragma unroll
        for (int mt = 0; mt < 2; ++mt)
#pragma unroll
            for (int nt = 0; nt < 4; ++nt)
#pragma unroll
                for (int r = 0; r < 4; ++r) S[mt][nt][r] = 0.f;

        __builtin_amdgcn_s_setprio(1);
#pragma unroll
        for (int nt = 0; nt < 4; ++nt)
#pragma unroll
            for (int c = 0; c < 2; ++c) {
                bf16x8 kf = *reinterpret_cast<const bf16x8*>(
                    &Ks[(nt * 16 + fr) * LDA + c * 32 + fq * 8]);
#pragma unroll
                for (int mt = 0; mt < 2; ++mt)
                    S[mt][nt] = __builtin_amdgcn_mfma_f32_16x16x32_bf16(
                        kf, qf[mt][c], S[mt][nt], 0, 0, 0);
            }
        __builtin_amdgcn_s_setprio(0);

        // ---- T14: issue next-tile K/V loads; drain under softmax+PV ----
        const bool more = (t + KVB < S_LEN);
        bf16x8 kv0n, kv1n, vv0n, vv1n;
        if (more) {
            const ushort_t* kp = kbase + (size_t)(t + KVB) * HID_C;
            const ushort_t* vp = vbase + (t + KVB);
            kv0n = *reinterpret_cast<const bf16x8*>(kp);
            kv1n = *reinterpret_cast<const bf16x8*>(kp + 8);
            vv0n = *reinterpret_cast<const bf16x8*>(vp);
            vv1n = *reinterpret_cast<const bf16x8*>(vp + 8);
        }

        // ---- mask add + in-register row max (q = mt*16+fr, lane-local k) ----
        float mx[2];
        int okl = 1;
#pragma unroll
        for (int mt = 0; mt < 2; ++mt) {
#pragma unroll
            for (int nt = 0; nt < 4; ++nt)
#pragma unroll
                for (int r = 0; r < 4; ++r) S[mt][nt][r] += mbv[nt][r];
            float v0 = fmaxf(fmaxf(S[mt][0][0], S[mt][0][1]),
                             fmaxf(S[mt][0][2], S[mt][0][3]));
            float v1 = fmaxf(fmaxf(S[mt][1][0], S[mt][1][1]),
                             fmaxf(S[mt][1][2], S[mt][1][3]));
            float v2 = fmaxf(fmaxf(S[mt][2][0], S[mt][2][1]),
                             fmaxf(S[mt][2][2], S[mt][2][3]));
            float v3 = fmaxf(fmaxf(S[mt][3][0], S[mt][3][1]),
                             fmaxf(S[mt][3][2], S[mt][3][3]));
            float v = fmaxf(fmaxf(v0, v1), fmaxf(v2, v3));
            v = fmaxf(v, __shfl_xor(v, 16));
            v = fmaxf(v, __shfl_xor(v, 32));
            mx[mt] = v;
            okl &= (v <= m_[mt] + 8.f);
        }

        // ---- rare rescale branch (defer-max, THR=8) ----
        if (!__all(okl)) {
            float corr[2];
#pragma unroll
            for (int mt = 0; mt < 2; ++mt) {
                float mn = fmaxf(m_[mt], mx[mt]);
                corr[mt] = exp2f(m_[mt] - mn);
                m_[mt] = mn;
                l_[mt] *= corr[mt];
                if (fq == 0) XposeA[w * 32 + mt * 16 + fr] = corr[mt];
            }
            // same-wave RAW on LDS: compiler inserts lgkmcnt
#pragma unroll
            for (int mt2 = 0; mt2 < 2; ++mt2)
#pragma unroll
                for (int r = 0; r < 4; ++r) {
                    float cq = XposeA[w * 32 + mt2 * 16 + fq * 4 + r];
#pragma unroll
                    for (int dt = 0; dt < 4; ++dt) OV[mt2][dt][r] *= cq;
                }
        }

        // ---- P = exp2(S - m), in-reg row-sum, packed b64 stage ----
#pragma unroll
        for (int mt = 0; mt < 2; ++mt) {
            float ls = 0.f;
#pragma unroll
            for (int nt = 0; nt < 4; ++nt) {
                float p0 = exp2f(S[mt][nt][0] - m_[mt]);
                float p1 = exp2f(S[mt][nt][1] - m_[mt]);
                float p2 = exp2f(S[mt][nt][2] - m_[mt]);
                float p3 = exp2f(S[mt][nt][3] - m_[mt]);
                ls += (p0 + p1) + (p2 + p3);
                uint2 pk;
                pk.x = ((unsigned int)f32_to_bf16_rn(p1) << 16) | f32_to_bf16_rn(p0);
                pk.y = ((unsigned int)f32_to_bf16_rn(p3) << 16) | f32_to_bf16_rn(p2);
                *reinterpret_cast<uint2*>(
                    &Ps[(w * 32 + mt * 16 + fr) * LDA + nt * 16 + fq * 4]) = pk;
            }
            ls += __shfl_xor(ls, 16);
            ls += __shfl_xor(ls, 32);
            l_[mt] += ls;
        }
        // wave-private Ps region: writer == reader wave.

        // ---- PV ----
        bf16x8 pf[2][2];
#pragma unroll
        for (int mt = 0; mt < 2; ++mt)
#pragma unroll
            for (int c = 0; c < 2; ++c)
                pf[mt][c] = *reinterpret_cast<const bf16x8*>(
                    &Ps[(w * 32 + mt * 16 + fr) * LDA + c * 32 + fq * 8]);

        __builtin_amdgcn_s_setprio(1);
#pragma unroll
        for (int dt = 0; dt < 4; ++dt)
#pragma unroll
            for (int c = 0; c < 2; ++c) {
                bf16x8 vf = *reinterpret_cast<const bf16x8*>(
                    &Vt[(dt * 16 + fr) * LDA + c * 32 + fq * 8]);
#pragma unroll
                for (int mt = 0; mt < 2; ++mt)
                    OV[mt][dt] = __builtin_amdgcn_mfma_f32_16x16x32_bf16(
                        pf[mt][c], vf, OV[mt][dt], 0, 0, 0);
            }
        __builtin_amdgcn_s_setprio(0);

        // ---- stage next tile ----
        __syncthreads();
        if (more) {
            *reinterpret_cast<bf16x8*>(&Ks[sr * LDA + seg * 16])     = kv0n;
            *reinterpret_cast<bf16x8*>(&Ks[sr * LDA + seg * 16 + 8]) = kv1n;
            *reinterpret_cast<bf16x8*>(&Vt[sr * LDA + seg * 16])     = vv0n;
            *reinterpret_cast<bf16x8*>(&Vt[sr * LDA + seg * 16 + 8]) = vv1n;
            __syncthreads();
        }
    }

    // ---- epilogue: transpose 1/l (q=fr domain -> q=fq*4+r domain) ----
    if (fq == 0) {
        XposeA[w * 32 + fr]      = 1.f / l_[0];
        XposeA[w * 32 + 16 + fr] = 1.f / l_[1];
    }
    // same-wave RAW: compiler inserts lgkmcnt
#pragma unroll
    for (int mt = 0; mt < 2; ++mt)
#pragma unroll
        for (int r = 0; r < 4; ++r) {
            const float inv = XposeA[w * 32 + mt * 16 + fq * 4 + r];
            const size_t row = bS + q0 + w * 32 + mt * 16 + fq * 4 + r;
#pragma unroll
            for (int dt = 0; dt < 4; ++dt) {
                float v = OV[mt][dt][r] * inv;
                unsigned int u = __float_as_uint(v);
                unsigned short hi = (unsigned short)(u >> 16);
                float res = v - __uint_as_float(u & 0xFFFF0000u);
                Xhi[row * HID_C + hc + dt * 16 + fr] = hi;
                Xlo[row * HID_C + hc + dt * 16 + fr] = f32_to_bf16_rn(res);
            }
        }
}

// ---------------------------------------------------------------------------
extern "C" void kernel_launch(void* const* d_in, const int* in_sizes, int n_in,
                              void* d_out, int out_size, void* d_ws, size_t ws_size,
                              hipStream_t stream) {
    const float* query = (const float*)d_in[0];
    const float* key   = (const float*)d_in[1];
    const float* value = (const float*)d_in[2];
    const int*   mask  = (const int*)d_in[3];
    const float* Wq = (const float*)d_in[4];
    const float* bq = (const float*)d_in[5];
    const float* Wk = (const float*)d_in[6];
    const float* bk = (const float*)d_in[7];
    const float* Wv = (const float*)d_in[8];
    const float* bv = (const float*)d_in[9];
    const float* Wo = (const float*)d_in[10];
    const float* bo = (const float*)d_in[11];
    float* out = (float*)d_out;

    const int B = 4, M = B * S_LEN;          // 8192
    const size_t seg = (size_t)M * HID_C;

    ushort_t* Qb  = (ushort_t*)d_ws;         // 16MB each
    ushort_t* Kb  = Qb + seg;
    ushort_t* Vtg = Kb + seg;                // V^T: [1024 feat][8192 tok]
    ushort_t* Xhi = Vtg + seg;
    ushort_t* Xlo = Xhi + seg;
    float*    Mb  = (float*)(Xlo + seg);     // mask bias: 32KB

    mask_to_bias<<<dim3(M / 256), 256, 0, stream>>>(mask, Mb, M);

    const float SC2 = 0.125f * LOG2E;
    dim3 gg(HID_C / BN, M / BM);             // (8, 64)
    gemm_xwt_bias_mfma<1, 0><<<gg, 256, 0, stream>>>(
        query, nullptr, nullptr, Wq, bq, nullptr, Qb, M, HID_C, HID_C, SC2);
    gemm_xwt_bias_mfma<1, 0><<<gg, 256, 0, stream>>>(
        key,   nullptr, nullptr, Wk, bk, nullptr, Kb, M, HID_C, HID_C, 1.f);
    dim3 gv(M / BN, HID_C / BM);             // (64, 8)
    gemm_xwt_bias_mfma<2, 0><<<gv, 256, 0, stream>>>(
        Wv, nullptr, nullptr, value, bv, nullptr, Vtg, HID_C, M, HID_C, 1.f);

    dim3 ga(S_LEN / QBLK, B * NHEADS);       // (16, 64)
    flash_attn_bf16<<<ga, 256, 0, stream>>>(Qb, Kb, Vtg, Mb, Xhi, Xlo);

    gemm_xwt_bias_mfma<0, 1><<<gg, 256, 0, stream>>>(
        nullptr, Xhi, Xlo, Wo, bo, out, nullptr, M, HID_C, HID_C, 1.f);
}

// Round 8
// 356.646 us; speedup vs baseline: 1.3174x; 1.0617x over previous
//
#include <hip/hip_runtime.h>
#include <cstddef>
#include <math.h>

#define S_LEN  2048
#define HID_C  1024
#define NHEADS 16
#define HDIM   64

typedef __attribute__((ext_vector_type(8))) short bf16x8;
typedef __attribute__((ext_vector_type(4))) float f32x4;
typedef unsigned short ushort_t;

#define LOG2E 1.44269504088896f

// cheap round-to-nearest fp32 -> bf16 (ties-up; same 1/2-ulp bound as RNE)
__device__ __forceinline__ unsigned short f32_to_bf16_rn(float f) {
    unsigned int u = __float_as_uint(f);
    return (unsigned short)((u + 0x8000u) >> 16);
}

// ---------------------------------------------------------------------------
// prep: weights -> bf16 (Wq/Wk/Wo), Wv -> hi/lo split, mask -> f32 bias
// ---------------------------------------------------------------------------
__global__ void prep_inputs(const float* __restrict__ Wq, const float* __restrict__ Wk,
                            const float* __restrict__ Wo, const float* __restrict__ Wv,
                            const int* __restrict__ mask,
                            ushort_t* __restrict__ Wqb, ushort_t* __restrict__ Wkb,
                            ushort_t* __restrict__ Wob, ushort_t* __restrict__ Wvh,
                            ushort_t* __restrict__ Wvl, float* __restrict__ Mb) {
    unsigned i = blockIdx.x * 256 + threadIdx.x;
    const unsigned NW = HID_C * HID_C;
    if (i < NW) { Wqb[i] = f32_to_bf16_rn(Wq[i]); return; }
    i -= NW;
    if (i < NW) { Wkb[i] = f32_to_bf16_rn(Wk[i]); return; }
    i -= NW;
    if (i < NW) { Wob[i] = f32_to_bf16_rn(Wo[i]); return; }
    i -= NW;
    if (i < NW) {
        float f = Wv[i];
        unsigned u = __float_as_uint(f);
        Wvh[i] = (ushort_t)(u >> 16);
        Wvl[i] = f32_to_bf16_rn(f - __uint_as_float(u & 0xFFFF0000u));
        return;
    }
    i -= NW;
    if (i < 4 * S_LEN) Mb[i] = mask[i] ? 0.f : -1e30f;
}

// ---------------------------------------------------------------------------
// MFMA GEMM, split-A: out[m,n] = (sum_k X[m,k]*W[n,k] + bias) * oscale
// OMODE 0: fp32 out, col bias. OMODE 1: bf16 out, col bias.
// OMODE 2: bf16 out, ROW bias (swapped V^T GEMM).
// ASPLIT 0: fp32 A source (split in-kernel). ASPLIT 1: pre-split bf16 hi/lo.
// WB 0: fp32 W source (round in-kernel). WB 1: pre-rounded bf16 W.
// 128x128 tile, BK=32, 4 waves (2x2), 64x64/wave. LDS rows 40 shorts.
// ---------------------------------------------------------------------------
#define BM 128
#define BN 128
#define BKg 32
#define LDKg 40

template <int OMODE, int ASPLIT, int WB>
__global__ __launch_bounds__(256) void gemm_xwt_bias_mfma(
    const float* __restrict__ Xf,
    const ushort_t* __restrict__ Xhi, const ushort_t* __restrict__ Xlo,
    const float* __restrict__ Wf, const ushort_t* __restrict__ Wb,
    const float* __restrict__ bias,
    float* __restrict__ outF, ushort_t* __restrict__ outB,
    int M, int N, int K, float oscale)
{
    __shared__ __align__(16) short Ah[BM * LDKg];
    __shared__ __align__(16) short Al[BM * LDKg];
    __shared__ __align__(16) short Bh[BM * LDKg];

    const int tid  = threadIdx.x;
    const int lane = tid & 63;
    const int wave = tid >> 6;
    const int bm = blockIdx.y * BM;
    const int bn = blockIdx.x * BN;
    const int wm = (wave >> 1) * 64;
    const int wn = (wave & 1) * 64;

    const int sr = tid >> 1;
    const int sc = (tid & 1) * 16;

    f32x4 acc[4][4];
#pragma unroll
    for (int i = 0; i < 4; ++i)
#pragma unroll
        for (int j = 0; j < 4; ++j)
#pragma unroll
            for (int r = 0; r < 4; ++r) acc[i][j][r] = 0.f;

    const int fr = lane & 15;
    const int kb = (lane >> 4) * 8;

    for (int k0 = 0; k0 < K; k0 += BKg) {
        // ---- A prep ----
        bf16x8 xr0, xr1, lr0, lr1;
        if (ASPLIT == 0) {
            const float* Xp = Xf + (size_t)(bm + sr) * K + sc + k0;
            float xv[16];
#pragma unroll
            for (int q = 0; q < 4; ++q) {
                float4 a = *reinterpret_cast<const float4*>(Xp + q * 4);
                xv[q*4+0]=a.x; xv[q*4+1]=a.y; xv[q*4+2]=a.z; xv[q*4+3]=a.w;
            }
            short xh[16], xl[16];
#pragma unroll
            for (int j = 0; j < 16; ++j) {
                unsigned int u = __float_as_uint(xv[j]);
                xh[j] = (short)(u >> 16);
                float res = xv[j] - __uint_as_float(u & 0xFFFF0000u);
                xl[j] = (short)f32_to_bf16_rn(res);
            }
            xr0 = *reinterpret_cast<bf16x8*>(&xh[0]);
            xr1 = *reinterpret_cast<bf16x8*>(&xh[8]);
            lr0 = *reinterpret_cast<bf16x8*>(&xl[0]);
            lr1 = *reinterpret_cast<bf16x8*>(&xl[8]);
        } else {
            const ushort_t* hp = Xhi + (size_t)(bm + sr) * K + sc + k0;
            const ushort_t* lp = Xlo + (size_t)(bm + sr) * K + sc + k0;
            xr0 = *reinterpret_cast<const bf16x8*>(hp);
            xr1 = *reinterpret_cast<const bf16x8*>(hp + 8);
            lr0 = *reinterpret_cast<const bf16x8*>(lp);
            lr1 = *reinterpret_cast<const bf16x8*>(lp + 8);
        }
        // ---- W prep ----
        bf16x8 wr0, wr1;
        if (WB == 1) {
            const ushort_t* wp = Wb + (size_t)(bn + sr) * K + sc + k0;
            wr0 = *reinterpret_cast<const bf16x8*>(wp);
            wr1 = *reinterpret_cast<const bf16x8*>(wp + 8);
        } else {
            const float* Wp = Wf + (size_t)(bn + sr) * K + sc + k0;
            float wv[16];
#pragma unroll
            for (int q = 0; q < 4; ++q) {
                float4 bq4 = *reinterpret_cast<const float4*>(Wp + q * 4);
                wv[q*4+0]=bq4.x; wv[q*4+1]=bq4.y; wv[q*4+2]=bq4.z; wv[q*4+3]=bq4.w;
            }
            short wh[16];
#pragma unroll
            for (int j = 0; j < 16; ++j) wh[j] = (short)f32_to_bf16_rn(wv[j]);
            wr0 = *reinterpret_cast<bf16x8*>(&wh[0]);
            wr1 = *reinterpret_cast<bf16x8*>(&wh[8]);
        }

        __syncthreads();    // prev-iter LDS reads done
        const int wbase = sr * LDKg + sc;
        *reinterpret_cast<bf16x8*>(&Ah[wbase])     = xr0;
        *reinterpret_cast<bf16x8*>(&Ah[wbase + 8]) = xr1;
        *reinterpret_cast<bf16x8*>(&Al[wbase])     = lr0;
        *reinterpret_cast<bf16x8*>(&Al[wbase + 8]) = lr1;
        *reinterpret_cast<bf16x8*>(&Bh[wbase])     = wr0;
        *reinterpret_cast<bf16x8*>(&Bh[wbase + 8]) = wr1;
        __syncthreads();

        bf16x8 fah[4], fal[4], fbh[4];
#pragma unroll
        for (int mi = 0; mi < 4; ++mi) {
            const int ra = (wm + mi * 16 + fr) * LDKg + kb;
            fah[mi] = *reinterpret_cast<const bf16x8*>(&Ah[ra]);
            fal[mi] = *reinterpret_cast<const bf16x8*>(&Al[ra]);
        }
#pragma unroll
        for (int ni = 0; ni < 4; ++ni) {
            const int rb = (wn + ni * 16 + fr) * LDKg + kb;
            fbh[ni] = *reinterpret_cast<const bf16x8*>(&Bh[rb]);
        }

#pragma unroll
        for (int mi = 0; mi < 4; ++mi)
#pragma unroll
            for (int ni = 0; ni < 4; ++ni) {
                acc[mi][ni] = __builtin_amdgcn_mfma_f32_16x16x32_bf16(
                    fah[mi], fbh[ni], acc[mi][ni], 0, 0, 0);
                acc[mi][ni] = __builtin_amdgcn_mfma_f32_16x16x32_bf16(
                    fal[mi], fbh[ni], acc[mi][ni], 0, 0, 0);
            }
    }

    const int fq = lane >> 4;
    if (OMODE == 2) {
#pragma unroll
        for (int mi = 0; mi < 4; ++mi) {
#pragma unroll
            for (int r = 0; r < 4; ++r) {
                const int row = bm + wm + mi * 16 + fq * 4 + r;
                const float bvr = bias[row];
#pragma unroll
                for (int ni = 0; ni < 4; ++ni) {
                    const int col = bn + wn + ni * 16 + fr;
                    outB[(size_t)row * N + col] =
                        f32_to_bf16_rn((acc[mi][ni][r] + bvr) * oscale);
                }
            }
        }
    } else {
        float bv[4];
#pragma unroll
        for (int ni = 0; ni < 4; ++ni) bv[ni] = bias[bn + wn + ni * 16 + fr];
#pragma unroll
        for (int mi = 0; mi < 4; ++mi)
#pragma unroll
            for (int ni = 0; ni < 4; ++ni) {
                const size_t rowb = (size_t)(bm + wm + mi * 16 + fq * 4);
                const int col = bn + wn + ni * 16 + fr;
#pragma unroll
                for (int r = 0; r < 4; ++r) {
                    float v = (acc[mi][ni][r] + bv[ni]) * oscale;
                    if (OMODE == 0) outF[(rowb + r) * N + col] = v;
                    else            outB[(rowb + r) * N + col] = f32_to_bf16_rn(v);
                }
            }
    }
}

// ---------------------------------------------------------------------------
// Flash attention, bf16 MFMA, SWAPPED QK^T (unchanged from R7 except the
// XCD-affinity grid decode): all 16 q-tiles of one (b,h) land on one XCD so
// K/V stay resident in that XCD's 4MB L2 (8 bh-groups x 512KB = 4MB).
// ---------------------------------------------------------------------------
#define QBLK 128
#define KVB  64
#define LDA  72

__global__ __launch_bounds__(256) void flash_attn_bf16(
    const ushort_t* __restrict__ Qb, const ushort_t* __restrict__ Kb,
    const ushort_t* __restrict__ Vtg, const float* __restrict__ maskb,
    ushort_t* __restrict__ Xhi, ushort_t* __restrict__ Xlo)
{
    __shared__ __align__(16) ushort_t Ks[KVB * LDA];
    __shared__ __align__(16) ushort_t Vt[HDIM * LDA];
    __shared__ __align__(16) ushort_t Ps[QBLK * LDA];
    __shared__ float XposeA[QBLK];

    // XCD-affinity decode: XCD slot = n&7 hosts bh in {8*(n&7) .. 8*(n&7)+7}
    const int n  = blockIdx.x;
    const int bh = (n & 7) * 8 + ((n >> 3) & 7);
    const int qx = n >> 6;
    const int b  = bh >> 4;
    const int h  = bh & 15;
    const int q0 = qx * QBLK;

    const int tid  = threadIdx.x;
    const int lane = tid & 63;
    const int w    = tid >> 6;
    const int fr = lane & 15;
    const int fq = lane >> 4;

    const size_t bS = (size_t)b * S_LEN;
    const int hc = h * HDIM;

    bf16x8 qf[2][2];
#pragma unroll
    for (int mt = 0; mt < 2; ++mt)
#pragma unroll
        for (int c = 0; c < 2; ++c)
            qf[mt][c] = *reinterpret_cast<const bf16x8*>(
                &Qb[(bS + q0 + w * 32 + mt * 16 + fr) * HID_C + hc + c * 32 + fq * 8]);

    f32x4 OV[2][4];
    float m_[2], l_[2];
#pragma unroll
    for (int mt = 0; mt < 2; ++mt) {
        m_[mt] = -1e30f; l_[mt] = 0.f;
#pragma unroll
        for (int dt = 0; dt < 4; ++dt)
#pragma unroll
            for (int r = 0; r < 4; ++r) OV[mt][dt][r] = 0.f;
    }

    const int sr  = tid >> 2;
    const int seg = tid & 3;
    const ushort_t* kbase = &Kb[(bS + sr) * HID_C + hc + seg * 16];
    const ushort_t* vbase = &Vtg[(size_t)(hc + sr) * (4 * S_LEN) + bS + seg * 16];

    {
        bf16x8 kv0 = *reinterpret_cast<const bf16x8*>(kbase);
        bf16x8 kv1 = *reinterpret_cast<const bf16x8*>(kbase + 8);
        bf16x8 vv0 = *reinterpret_cast<const bf16x8*>(vbase);
        bf16x8 vv1 = *reinterpret_cast<const bf16x8*>(vbase + 8);
        *reinterpret_cast<bf16x8*>(&Ks[sr * LDA + seg * 16])     = kv0;
        *reinterpret_cast<bf16x8*>(&Ks[sr * LDA + seg * 16 + 8]) = kv1;
        *reinterpret_cast<bf16x8*>(&Vt[sr * LDA + seg * 16])     = vv0;
        *reinterpret_cast<bf16x8*>(&Vt[sr * LDA + seg * 16 + 8]) = vv1;
        __syncthreads();
    }

    for (int t = 0; t < S_LEN; t += KVB) {
        float4 mbv[4];
#pragma unroll
        for (int nt = 0; nt < 4; ++nt)
            mbv[nt] = *reinterpret_cast<const float4*>(&maskb[bS + t + nt * 16 + fq * 4]);

        f32x4 S[2][4];
#pragma unroll
        for (int mt = 0; mt < 2; ++mt)
#pragma unroll
            for (int nt = 0; nt < 4; ++nt)
#pragma unroll
                for (int r = 0; r < 4; ++r) S[mt][nt][r] = 0.f;

        __builtin_amdgcn_s_setprio(1);
#pragma unroll
        for (int nt = 0; nt < 4; ++nt)
#pragma unroll
            for (int c = 0; c < 2; ++c) {
                bf16x8 kf = *reinterpret_cast<const bf16x8*>(
                    &Ks[(nt * 16 + fr) * LDA + c * 32 + fq * 8]);
#pragma unroll
                for (int mt = 0; mt < 2; ++mt)
                    S[mt][nt] = __builtin_amdgcn_mfma_f32_16x16x32_bf16(
                        kf, qf[mt][c], S[mt][nt], 0, 0, 0);
            }
        __builtin_amdgcn_s_setprio(0);

        const bool more = (t + KVB < S_LEN);
        bf16x8 kv0n, kv1n, vv0n, vv1n;
        if (more) {
            const ushort_t* kp = kbase + (size_t)(t + KVB) * HID_C;
            const ushort_t* vp = vbase + (t + KVB);
            kv0n = *reinterpret_cast<const bf16x8*>(kp);
            kv1n = *reinterpret_cast<const bf16x8*>(kp + 8);
            vv0n = *reinterpret_cast<const bf16x8*>(vp);
            vv1n = *reinterpret_cast<const bf16x8*>(vp + 8);
        }

        float mx[2];
        int okl = 1;
#pragma unroll
        for (int mt = 0; mt < 2; ++mt) {
#pragma unroll
            for (int nt = 0; nt < 4; ++nt)
#pragma unroll
                for (int r = 0; r < 4; ++r) S[mt][nt][r] += mbv[nt][r];
            float v0 = fmaxf(fmaxf(S[mt][0][0], S[mt][0][1]),
                             fmaxf(S[mt][0][2], S[mt][0][3]));
            float v1 = fmaxf(fmaxf(S[mt][1][0], S[mt][1][1]),
                             fmaxf(S[mt][1][2], S[mt][1][3]));
            float v2 = fmaxf(fmaxf(S[mt][2][0], S[mt][2][1]),
                             fmaxf(S[mt][2][2], S[mt][2][3]));
            float v3 = fmaxf(fmaxf(S[mt][3][0], S[mt][3][1]),
                             fmaxf(S[mt][3][2], S[mt][3][3]));
            float v = fmaxf(fmaxf(v0, v1), fmaxf(v2, v3));
            v = fmaxf(v, __shfl_xor(v, 16));
            v = fmaxf(v, __shfl_xor(v, 32));
            mx[mt] = v;
            okl &= (v <= m_[mt] + 8.f);
        }

        if (!__all(okl)) {
            float corr[2];
#pragma unroll
            for (int mt = 0; mt < 2; ++mt) {
                float mn = fmaxf(m_[mt], mx[mt]);
                corr[mt] = exp2f(m_[mt] - mn);
                m_[mt] = mn;
                l_[mt] *= corr[mt];
                if (fq == 0) XposeA[w * 32 + mt * 16 + fr] = corr[mt];
            }
#pragma unroll
            for (int mt2 = 0; mt2 < 2; ++mt2)
#pragma unroll
                for (int r = 0; r < 4; ++r) {
                    float cq = XposeA[w * 32 + mt2 * 16 + fq * 4 + r];
#pragma unroll
                    for (int dt = 0; dt < 4; ++dt) OV[mt2][dt][r] *= cq;
                }
        }

#pragma unroll
        for (int mt = 0; mt < 2; ++mt) {
            float ls = 0.f;
#pragma unroll
            for (int nt = 0; nt < 4; ++nt) {
                float p0 = exp2f(S[mt][nt][0] - m_[mt]);
                float p1 = exp2f(S[mt][nt][1] - m_[mt]);
                float p2 = exp2f(S[mt][nt][2] - m_[mt]);
                float p3 = exp2f(S[mt][nt][3] - m_[mt]);
                ls += (p0 + p1) + (p2 + p3);
                uint2 pk;
                pk.x = ((unsigned int)f32_to_bf16_rn(p1) << 16) | f32_to_bf16_rn(p0);
                pk.y = ((unsigned int)f32_to_bf16_rn(p3) << 16) | f32_to_bf16_rn(p2);
                *reinterpret_cast<uint2*>(
                    &Ps[(w * 32 + mt * 16 + fr) * LDA + nt * 16 + fq * 4]) = pk;
            }
            ls += __shfl_xor(ls, 16);
            ls += __shfl_xor(ls, 32);
            l_[mt] += ls;
        }

        bf16x8 pf[2][2];
#pragma unroll
        for (int mt = 0; mt < 2; ++mt)
#pragma unroll
            for (int c = 0; c < 2; ++c)
                pf[mt][c] = *reinterpret_cast<const bf16x8*>(
                    &Ps[(w * 32 + mt * 16 + fr) * LDA + c * 32 + fq * 8]);

        __builtin_amdgcn_s_setprio(1);
#pragma unroll
        for (int dt = 0; dt < 4; ++dt)
#pragma unroll
            for (int c = 0; c < 2; ++c) {
                bf16x8 vf = *reinterpret_cast<const bf16x8*>(
                    &Vt[(dt * 16 + fr) * LDA + c * 32 + fq * 8]);
#pragma unroll
                for (int mt = 0; mt < 2; ++mt)
                    OV[mt][dt] = __builtin_amdgcn_mfma_f32_16x16x32_bf16(
                        pf[mt][c], vf, OV[mt][dt], 0, 0, 0);
            }
        __builtin_amdgcn_s_setprio(0);

        __syncthreads();
        if (more) {
            *reinterpret_cast<bf16x8*>(&Ks[sr * LDA + seg * 16])     = kv0n;
            *reinterpret_cast<bf16x8*>(&Ks[sr * LDA + seg * 16 + 8]) = kv1n;
            *reinterpret_cast<bf16x8*>(&Vt[sr * LDA + seg * 16])     = vv0n;
            *reinterpret_cast<bf16x8*>(&Vt[sr * LDA + seg * 16 + 8]) = vv1n;
            __syncthreads();
        }
    }

    if (fq == 0) {
        XposeA[w * 32 + fr]      = 1.f / l_[0];
        XposeA[w * 32 + 16 + fr] = 1.f / l_[1];
    }
#pragma unroll
    for (int mt = 0; mt < 2; ++mt)
#pragma unroll
        for (int r = 0; r < 4; ++r) {
            const float inv = XposeA[w * 32 + mt * 16 + fq * 4 + r];
            const size_t row = bS + q0 + w * 32 + mt * 16 + fq * 4 + r;
#pragma unroll
            for (int dt = 0; dt < 4; ++dt) {
                float v = OV[mt][dt][r] * inv;
                unsigned int u = __float_as_uint(v);
                unsigned short hi = (unsigned short)(u >> 16);
                float res = v - __uint_as_float(u & 0xFFFF0000u);
                Xhi[row * HID_C + hc + dt * 16 + fr] = hi;
                Xlo[row * HID_C + hc + dt * 16 + fr] = f32_to_bf16_rn(res);
            }
        }
}

// ---------------------------------------------------------------------------
extern "C" void kernel_launch(void* const* d_in, const int* in_sizes, int n_in,
                              void* d_out, int out_size, void* d_ws, size_t ws_size,
                              hipStream_t stream) {
    const float* query = (const float*)d_in[0];
    const float* key   = (const float*)d_in[1];
    const float* value = (const float*)d_in[2];
    const int*   mask  = (const int*)d_in[3];
    const float* Wq = (const float*)d_in[4];
    const float* bq = (const float*)d_in[5];
    const float* Wk = (const float*)d_in[6];
    const float* bk = (const float*)d_in[7];
    const float* Wv = (const float*)d_in[8];
    const float* bv = (const float*)d_in[9];
    const float* Wo = (const float*)d_in[10];
    const float* bo = (const float*)d_in[11];
    float* out = (float*)d_out;

    const int B = 4, M = B * S_LEN;          // 8192
    const size_t seg = (size_t)M * HID_C;
    const size_t nw  = (size_t)HID_C * HID_C;

    ushort_t* Qb  = (ushort_t*)d_ws;         // 16MB each
    ushort_t* Kb  = Qb + seg;
    ushort_t* Vtg = Kb + seg;                // V^T: [1024 feat][8192 tok]
    ushort_t* Xhi = Vtg + seg;
    ushort_t* Xlo = Xhi + seg;
    float*    Mb  = (float*)(Xlo + seg);     // 32KB
    ushort_t* Wqb = (ushort_t*)(Mb + 4 * S_LEN);
    ushort_t* Wkb = Wqb + nw;                // 2MB each
    ushort_t* Wob = Wkb + nw;
    ushort_t* Wvh = Wob + nw;
    ushort_t* Wvl = Wvh + nw;                // total ~90MB

    {
        unsigned total = 4u * (unsigned)nw + 4 * S_LEN;
        prep_inputs<<<dim3((total + 255) / 256), 256, 0, stream>>>(
            Wq, Wk, Wo, Wv, mask, Wqb, Wkb, Wob, Wvh, Wvl, Mb);
    }

    const float SC2 = 0.125f * LOG2E;
    dim3 gg(HID_C / BN, M / BM);             // (8, 64)
    gemm_xwt_bias_mfma<1, 0, 1><<<gg, 256, 0, stream>>>(
        query, nullptr, nullptr, nullptr, Wqb, bq, nullptr, Qb, M, HID_C, HID_C, SC2);
    gemm_xwt_bias_mfma<1, 0, 1><<<gg, 256, 0, stream>>>(
        key, nullptr, nullptr, nullptr, Wkb, bk, nullptr, Kb, M, HID_C, HID_C, 1.f);
    dim3 gv(M / BN, HID_C / BM);             // (64, 8)
    gemm_xwt_bias_mfma<2, 1, 0><<<gv, 256, 0, stream>>>(
        nullptr, Wvh, Wvl, value, nullptr, bv, nullptr, Vtg, HID_C, M, HID_C, 1.f);

    flash_attn_bf16<<<dim3((S_LEN / QBLK) * B * NHEADS), 256, 0, stream>>>(
        Qb, Kb, Vtg, Mb, Xhi, Xlo);

    gemm_xwt_bias_mfma<0, 1, 1><<<gg, 256, 0, stream>>>(
        nullptr, Xhi, Xlo, nullptr, Wob, bo, out, nullptr, M, HID_C, HID_C, 1.f);
}

// Round 9
// 351.059 us; speedup vs baseline: 1.3383x; 1.0159x over previous
//
#include <hip/hip_runtime.h>
#include <cstddef>
#include <math.h>

#define S_LEN  2048
#define HID_C  1024
#define NHEADS 16
#define HDIM   64

typedef __attribute__((ext_vector_type(8))) short bf16x8;
typedef __attribute__((ext_vector_type(4))) float f32x4;
typedef unsigned short ushort_t;

#define LOG2E 1.44269504088896f

// cheap round-to-nearest fp32 -> bf16 (ties-up; same 1/2-ulp bound as RNE)
__device__ __forceinline__ unsigned short f32_to_bf16_rn(float f) {
    unsigned int u = __float_as_uint(f);
    return (unsigned short)((u + 0x8000u) >> 16);
}

// ---------------------------------------------------------------------------
// prep: Wq/Wk/Wo -> bf16, value -> bf16, mask -> f32 additive bias
// ---------------------------------------------------------------------------
__global__ void prep_inputs(const float* __restrict__ Wq, const float* __restrict__ Wk,
                            const float* __restrict__ Wo, const float* __restrict__ val,
                            const int* __restrict__ mask,
                            ushort_t* __restrict__ Wqb, ushort_t* __restrict__ Wkb,
                            ushort_t* __restrict__ Wob, ushort_t* __restrict__ Vb,
                            float* __restrict__ Mb) {
    unsigned i = blockIdx.x * 256 + threadIdx.x;
    const unsigned NW = HID_C * HID_C;
    const unsigned SEG = 4u * S_LEN * HID_C;
    if (i < NW) { Wqb[i] = f32_to_bf16_rn(Wq[i]); return; }
    i -= NW;
    if (i < NW) { Wkb[i] = f32_to_bf16_rn(Wk[i]); return; }
    i -= NW;
    if (i < NW) { Wob[i] = f32_to_bf16_rn(Wo[i]); return; }
    i -= NW;
    if (i < SEG) { Vb[i] = f32_to_bf16_rn(val[i]); return; }
    i -= SEG;
    if (i < 4 * S_LEN) Mb[i] = mask[i] ? 0.f : -1e30f;
}

// ---------------------------------------------------------------------------
// MFMA GEMM: out[m,n] = (sum_k X[m,k]*W[n,k] + bias) * oscale
// W source is always pre-rounded bf16 (Wb).
// AMODE 1: A = pre-split bf16 hi/lo (2 MFMA / pair — for the fp32-out O-GEMM).
// AMODE 2: A = fp32, rounded to plain bf16 in-kernel (1 MFMA — for bf16-out
//          GEMMs, where output quantization dominates input rounding).
// OMODE 0: fp32 out, col bias. OMODE 1: bf16 out, col bias.
// OMODE 2: bf16 out, ROW bias (swapped V^T GEMM).
// 128x128 tile, BK=32, 4 waves (2x2), 64x64/wave. LDS rows 40 shorts (80B).
// ---------------------------------------------------------------------------
#define BM 128
#define BN 128
#define BKg 32
#define LDKg 40

template <int OMODE, int AMODE>
__global__ __launch_bounds__(256) void gemm_xwt_bias_mfma(
    const float* __restrict__ Xf,
    const ushort_t* __restrict__ Xhi, const ushort_t* __restrict__ Xlo,
    const ushort_t* __restrict__ Wb, const float* __restrict__ bias,
    float* __restrict__ outF, ushort_t* __restrict__ outB,
    int M, int N, int K, float oscale)
{
    __shared__ __align__(16) short Ah[BM * LDKg];
    __shared__ __align__(16) short Al[(AMODE == 1) ? BM * LDKg : 8];
    __shared__ __align__(16) short Bh[BM * LDKg];

    const int tid  = threadIdx.x;
    const int lane = tid & 63;
    const int wave = tid >> 6;
    const int bm = blockIdx.y * BM;
    const int bn = blockIdx.x * BN;
    const int wm = (wave >> 1) * 64;
    const int wn = (wave & 1) * 64;

    const int sr = tid >> 1;
    const int sc = (tid & 1) * 16;

    f32x4 acc[4][4];
#pragma unroll
    for (int i = 0; i < 4; ++i)
#pragma unroll
        for (int j = 0; j < 4; ++j)
#pragma unroll
            for (int r = 0; r < 4; ++r) acc[i][j][r] = 0.f;

    const int fr = lane & 15;
    const int kb = (lane >> 4) * 8;

    for (int k0 = 0; k0 < K; k0 += BKg) {
        // ---- A prep ----
        bf16x8 xr0, xr1, lr0, lr1;
        if (AMODE == 2) {
            const float* Xp = Xf + (size_t)(bm + sr) * K + sc + k0;
            float xv[16];
#pragma unroll
            for (int q = 0; q < 4; ++q) {
                float4 a = *reinterpret_cast<const float4*>(Xp + q * 4);
                xv[q*4+0]=a.x; xv[q*4+1]=a.y; xv[q*4+2]=a.z; xv[q*4+3]=a.w;
            }
            short xh[16];
#pragma unroll
            for (int j = 0; j < 16; ++j) xh[j] = (short)f32_to_bf16_rn(xv[j]);
            xr0 = *reinterpret_cast<bf16x8*>(&xh[0]);
            xr1 = *reinterpret_cast<bf16x8*>(&xh[8]);
        } else {
            const ushort_t* hp = Xhi + (size_t)(bm + sr) * K + sc + k0;
            const ushort_t* lp = Xlo + (size_t)(bm + sr) * K + sc + k0;
            xr0 = *reinterpret_cast<const bf16x8*>(hp);
            xr1 = *reinterpret_cast<const bf16x8*>(hp + 8);
            lr0 = *reinterpret_cast<const bf16x8*>(lp);
            lr1 = *reinterpret_cast<const bf16x8*>(lp + 8);
        }
        // ---- W load (pre-rounded bf16) ----
        const ushort_t* wp = Wb + (size_t)(bn + sr) * K + sc + k0;
        bf16x8 wr0 = *reinterpret_cast<const bf16x8*>(wp);
        bf16x8 wr1 = *reinterpret_cast<const bf16x8*>(wp + 8);

        __syncthreads();    // prev-iter LDS reads done
        const int wbase = sr * LDKg + sc;
        *reinterpret_cast<bf16x8*>(&Ah[wbase])     = xr0;
        *reinterpret_cast<bf16x8*>(&Ah[wbase + 8]) = xr1;
        if (AMODE == 1) {
            *reinterpret_cast<bf16x8*>(&Al[wbase])     = lr0;
            *reinterpret_cast<bf16x8*>(&Al[wbase + 8]) = lr1;
        }
        *reinterpret_cast<bf16x8*>(&Bh[wbase])     = wr0;
        *reinterpret_cast<bf16x8*>(&Bh[wbase + 8]) = wr1;
        __syncthreads();

        bf16x8 fah[4], fal[4], fbh[4];
#pragma unroll
        for (int mi = 0; mi < 4; ++mi) {
            const int ra = (wm + mi * 16 + fr) * LDKg + kb;
            fah[mi] = *reinterpret_cast<const bf16x8*>(&Ah[ra]);
            if (AMODE == 1) fal[mi] = *reinterpret_cast<const bf16x8*>(&Al[ra]);
        }
#pragma unroll
        for (int ni = 0; ni < 4; ++ni) {
            const int rb = (wn + ni * 16 + fr) * LDKg + kb;
            fbh[ni] = *reinterpret_cast<const bf16x8*>(&Bh[rb]);
        }

#pragma unroll
        for (int mi = 0; mi < 4; ++mi)
#pragma unroll
            for (int ni = 0; ni < 4; ++ni) {
                acc[mi][ni] = __builtin_amdgcn_mfma_f32_16x16x32_bf16(
                    fah[mi], fbh[ni], acc[mi][ni], 0, 0, 0);
                if (AMODE == 1)
                    acc[mi][ni] = __builtin_amdgcn_mfma_f32_16x16x32_bf16(
                        fal[mi], fbh[ni], acc[mi][ni], 0, 0, 0);
            }
    }

    const int fq = lane >> 4;
    if (OMODE == 2) {
#pragma unroll
        for (int mi = 0; mi < 4; ++mi) {
#pragma unroll
            for (int r = 0; r < 4; ++r) {
                const int row = bm + wm + mi * 16 + fq * 4 + r;
                const float bvr = bias[row];
#pragma unroll
                for (int ni = 0; ni < 4; ++ni) {
                    const int col = bn + wn + ni * 16 + fr;
                    outB[(size_t)row * N + col] =
                        f32_to_bf16_rn((acc[mi][ni][r] + bvr) * oscale);
                }
            }
        }
    } else {
        float bv[4];
#pragma unroll
        for (int ni = 0; ni < 4; ++ni) bv[ni] = bias[bn + wn + ni * 16 + fr];
#pragma unroll
        for (int mi = 0; mi < 4; ++mi)
#pragma unroll
            for (int ni = 0; ni < 4; ++ni) {
                const size_t rowb = (size_t)(bm + wm + mi * 16 + fq * 4);
                const int col = bn + wn + ni * 16 + fr;
#pragma unroll
                for (int r = 0; r < 4; ++r) {
                    float v = (acc[mi][ni][r] + bv[ni]) * oscale;
                    if (OMODE == 0) outF[(rowb + r) * N + col] = v;
                    else            outB[(rowb + r) * N + col] = f32_to_bf16_rn(v);
                }
            }
    }
}

// ---------------------------------------------------------------------------
// Flash attention, bf16 MFMA, SWAPPED QK^T (unchanged from R8).
// XCD-affinity grid: all 16 q-tiles of one (b,h) on one XCD (K/V L2-resident).
// ---------------------------------------------------------------------------
#define QBLK 128
#define KVB  64
#define LDA  72

__global__ __launch_bounds__(256) void flash_attn_bf16(
    const ushort_t* __restrict__ Qb, const ushort_t* __restrict__ Kb,
    const ushort_t* __restrict__ Vtg, const float* __restrict__ maskb,
    ushort_t* __restrict__ Xhi, ushort_t* __restrict__ Xlo)
{
    __shared__ __align__(16) ushort_t Ks[KVB * LDA];
    __shared__ __align__(16) ushort_t Vt[HDIM * LDA];
    __shared__ __align__(16) ushort_t Ps[QBLK * LDA];
    __shared__ float XposeA[QBLK];

    const int n  = blockIdx.x;
    const int bh = (n & 7) * 8 + ((n >> 3) & 7);
    const int qx = n >> 6;
    const int b  = bh >> 4;
    const int h  = bh & 15;
    const int q0 = qx * QBLK;

    const int tid  = threadIdx.x;
    const int lane = tid & 63;
    const int w    = tid >> 6;
    const int fr = lane & 15;
    const int fq = lane >> 4;

    const size_t bS = (size_t)b * S_LEN;
    const int hc = h * HDIM;

    bf16x8 qf[2][2];
#pragma unroll
    for (int mt = 0; mt < 2; ++mt)
#pragma unroll
        for (int c = 0; c < 2; ++c)
            qf[mt][c] = *reinterpret_cast<const bf16x8*>(
                &Qb[(bS + q0 + w * 32 + mt * 16 + fr) * HID_C + hc + c * 32 + fq * 8]);

    f32x4 OV[2][4];
    float m_[2], l_[2];
#pragma unroll
    for (int mt = 0; mt < 2; ++mt) {
        m_[mt] = -1e30f; l_[mt] = 0.f;
#pragma unroll
        for (int dt = 0; dt < 4; ++dt)
#pragma unroll
            for (int r = 0; r < 4; ++r) OV[mt][dt][r] = 0.f;
    }

    const int sr  = tid >> 2;
    const int seg = tid & 3;
    const ushort_t* kbase = &Kb[(bS + sr) * HID_C + hc + seg * 16];
    const ushort_t* vbase = &Vtg[(size_t)(hc + sr) * (4 * S_LEN) + bS + seg * 16];

    {
        bf16x8 kv0 = *reinterpret_cast<const bf16x8*>(kbase);
        bf16x8 kv1 = *reinterpret_cast<const bf16x8*>(kbase + 8);
        bf16x8 vv0 = *reinterpret_cast<const bf16x8*>(vbase);
        bf16x8 vv1 = *reinterpret_cast<const bf16x8*>(vbase + 8);
        *reinterpret_cast<bf16x8*>(&Ks[sr * LDA + seg * 16])     = kv0;
        *reinterpret_cast<bf16x8*>(&Ks[sr * LDA + seg * 16 + 8]) = kv1;
        *reinterpret_cast<bf16x8*>(&Vt[sr * LDA + seg * 16])     = vv0;
        *reinterpret_cast<bf16x8*>(&Vt[sr * LDA + seg * 16 + 8]) = vv1;
        __syncthreads();
    }

    for (int t = 0; t < S_LEN; t += KVB) {
        float4 mbv[4];
#pragma unroll
        for (int nt = 0; nt < 4; ++nt)
            mbv[nt] = *reinterpret_cast<const float4*>(&maskb[bS + t + nt * 16 + fq * 4]);

        f32x4 S[2][4];
#pragma unroll
        for (int mt = 0; mt < 2; ++mt)
#pragma unroll
            for (int nt = 0; nt < 4; ++nt)
#pragma unroll
                for (int r = 0; r < 4; ++r) S[mt][nt][r] = 0.f;

        __builtin_amdgcn_s_setprio(1);
#pragma unroll
        for (int nt = 0; nt < 4; ++nt)
#pragma unroll
            for (int c = 0; c < 2; ++c) {
                bf16x8 kf = *reinterpret_cast<const bf16x8*>(
                    &Ks[(nt * 16 + fr) * LDA + c * 32 + fq * 8]);
#pragma unroll
                for (int mt = 0; mt < 2; ++mt)
                    S[mt][nt] = __builtin_amdgcn_mfma_f32_16x16x32_bf16(
                        kf, qf[mt][c], S[mt][nt], 0, 0, 0);
            }
        __builtin_amdgcn_s_setprio(0);

        const bool more = (t + KVB < S_LEN);
        bf16x8 kv0n, kv1n, vv0n, vv1n;
        if (more) {
            const ushort_t* kp = kbase + (size_t)(t + KVB) * HID_C;
            const ushort_t* vp = vbase + (t + KVB);
            kv0n = *reinterpret_cast<const bf16x8*>(kp);
            kv1n = *reinterpret_cast<const bf16x8*>(kp + 8);
            vv0n = *reinterpret_cast<const bf16x8*>(vp);
            vv1n = *reinterpret_cast<const bf16x8*>(vp + 8);
        }

        float mx[2];
        int okl = 1;
#pragma unroll
        for (int mt = 0; mt < 2; ++mt) {
#pragma unroll
            for (int nt = 0; nt < 4; ++nt)
#pragma unroll
                for (int r = 0; r < 4; ++r) S[mt][nt][r] += mbv[nt][r];
            float v0 = fmaxf(fmaxf(S[mt][0][0], S[mt][0][1]),
                             fmaxf(S[mt][0][2], S[mt][0][3]));
            float v1 = fmaxf(fmaxf(S[mt][1][0], S[mt][1][1]),
                             fmaxf(S[mt][1][2], S[mt][1][3]));
            float v2 = fmaxf(fmaxf(S[mt][2][0], S[mt][2][1]),
                             fmaxf(S[mt][2][2], S[mt][2][3]));
            float v3 = fmaxf(fmaxf(S[mt][3][0], S[mt][3][1]),
                             fmaxf(S[mt][3][2], S[mt][3][3]));
            float v = fmaxf(fmaxf(v0, v1), fmaxf(v2, v3));
            v = fmaxf(v, __shfl_xor(v, 16));
            v = fmaxf(v, __shfl_xor(v, 32));
            mx[mt] = v;
            okl &= (v <= m_[mt] + 8.f);
        }

        if (!__all(okl)) {
            float corr[2];
#pragma unroll
            for (int mt = 0; mt < 2; ++mt) {
                float mn = fmaxf(m_[mt], mx[mt]);
                corr[mt] = exp2f(m_[mt] - mn);
                m_[mt] = mn;
                l_[mt] *= corr[mt];
                if (fq == 0) XposeA[w * 32 + mt * 16 + fr] = corr[mt];
            }
#pragma unroll
            for (int mt2 = 0; mt2 < 2; ++mt2)
#pragma unroll
                for (int r = 0; r < 4; ++r) {
                    float cq = XposeA[w * 32 + mt2 * 16 + fq * 4 + r];
#pragma unroll
                    for (int dt = 0; dt < 4; ++dt) OV[mt2][dt][r] *= cq;
                }
        }

#pragma unroll
        for (int mt = 0; mt < 2; ++mt) {
            float ls = 0.f;
#pragma unroll
            for (int nt = 0; nt < 4; ++nt) {
                float p0 = exp2f(S[mt][nt][0] - m_[mt]);
                float p1 = exp2f(S[mt][nt][1] - m_[mt]);
                float p2 = exp2f(S[mt][nt][2] - m_[mt]);
                float p3 = exp2f(S[mt][nt][3] - m_[mt]);
                ls += (p0 + p1) + (p2 + p3);
                uint2 pk;
                pk.x = ((unsigned int)f32_to_bf16_rn(p1) << 16) | f32_to_bf16_rn(p0);
                pk.y = ((unsigned int)f32_to_bf16_rn(p3) << 16) | f32_to_bf16_rn(p2);
                *reinterpret_cast<uint2*>(
                    &Ps[(w * 32 + mt * 16 + fr) * LDA + nt * 16 + fq * 4]) = pk;
            }
            ls += __shfl_xor(ls, 16);
            ls += __shfl_xor(ls, 32);
            l_[mt] += ls;
        }

        bf16x8 pf[2][2];
#pragma unroll
        for (int mt = 0; mt < 2; ++mt)
#pragma unroll
            for (int c = 0; c < 2; ++c)
                pf[mt][c] = *reinterpret_cast<const bf16x8*>(
                    &Ps[(w * 32 + mt * 16 + fr) * LDA + c * 32 + fq * 8]);

        __builtin_amdgcn_s_setprio(1);
#pragma unroll
        for (int dt = 0; dt < 4; ++dt)
#pragma unroll
            for (int c = 0; c < 2; ++c) {
                bf16x8 vf = *reinterpret_cast<const bf16x8*>(
                    &Vt[(dt * 16 + fr) * LDA + c * 32 + fq * 8]);
#pragma unroll
                for (int mt = 0; mt < 2; ++mt)
                    OV[mt][dt] = __builtin_amdgcn_mfma_f32_16x16x32_bf16(
                        pf[mt][c], vf, OV[mt][dt], 0, 0, 0);
            }
        __builtin_amdgcn_s_setprio(0);

        __syncthreads();
        if (more) {
            *reinterpret_cast<bf16x8*>(&Ks[sr * LDA + seg * 16])     = kv0n;
            *reinterpret_cast<bf16x8*>(&Ks[sr * LDA + seg * 16 + 8]) = kv1n;
            *reinterpret_cast<bf16x8*>(&Vt[sr * LDA + seg * 16])     = vv0n;
            *reinterpret_cast<bf16x8*>(&Vt[sr * LDA + seg * 16 + 8]) = vv1n;
            __syncthreads();
        }
    }

    if (fq == 0) {
        XposeA[w * 32 + fr]      = 1.f / l_[0];
        XposeA[w * 32 + 16 + fr] = 1.f / l_[1];
    }
#pragma unroll
    for (int mt = 0; mt < 2; ++mt)
#pragma unroll
        for (int r = 0; r < 4; ++r) {
            const float inv = XposeA[w * 32 + mt * 16 + fq * 4 + r];
            const size_t row = bS + q0 + w * 32 + mt * 16 + fq * 4 + r;
#pragma unroll
            for (int dt = 0; dt < 4; ++dt) {
                float v = OV[mt][dt][r] * inv;
                unsigned int u = __float_as_uint(v);
                unsigned short hi = (unsigned short)(u >> 16);
                float res = v - __uint_as_float(u & 0xFFFF0000u);
                Xhi[row * HID_C + hc + dt * 16 + fr] = hi;
                Xlo[row * HID_C + hc + dt * 16 + fr] = f32_to_bf16_rn(res);
            }
        }
}

// ---------------------------------------------------------------------------
extern "C" void kernel_launch(void* const* d_in, const int* in_sizes, int n_in,
                              void* d_out, int out_size, void* d_ws, size_t ws_size,
                              hipStream_t stream) {
    const float* query = (const float*)d_in[0];
    const float* key   = (const float*)d_in[1];
    const float* value = (const float*)d_in[2];
    const int*   mask  = (const int*)d_in[3];
    const float* Wq = (const float*)d_in[4];
    const float* bq = (const float*)d_in[5];
    const float* Wk = (const float*)d_in[6];
    const float* bk = (const float*)d_in[7];
    const float* Wv = (const float*)d_in[8];
    const float* bv = (const float*)d_in[9];
    const float* Wo = (const float*)d_in[10];
    const float* bo = (const float*)d_in[11];
    float* out = (float*)d_out;

    const int B = 4, M = B * S_LEN;          // 8192
    const size_t seg = (size_t)M * HID_C;
    const size_t nw  = (size_t)HID_C * HID_C;

    ushort_t* Qb  = (ushort_t*)d_ws;         // 16MB each
    ushort_t* Kb  = Qb + seg;
    ushort_t* Vtg = Kb + seg;                // V^T: [1024 feat][8192 tok]
    ushort_t* Xhi = Vtg + seg;
    ushort_t* Xlo = Xhi + seg;
    ushort_t* Vb  = Xlo + seg;               // value pre-rounded bf16, 16MB
    float*    Mb  = (float*)(Vb + seg);      // 32KB
    ushort_t* Wqb = (ushort_t*)(Mb + 4 * S_LEN);
    ushort_t* Wkb = Wqb + nw;                // 2MB each
    ushort_t* Wob = Wkb + nw;                // total ~102MB

    {
        unsigned total = 3u * (unsigned)nw + (unsigned)seg + 4 * S_LEN;
        prep_inputs<<<dim3((total + 255) / 256), 256, 0, stream>>>(
            Wq, Wk, Wo, value, mask, Wqb, Wkb, Wob, Vb, Mb);
    }

    const float SC2 = 0.125f * LOG2E;
    dim3 gg(HID_C / BN, M / BM);             // (8, 64)
    gemm_xwt_bias_mfma<1, 2><<<gg, 256, 0, stream>>>(
        query, nullptr, nullptr, Wqb, bq, nullptr, Qb, M, HID_C, HID_C, SC2);
    gemm_xwt_bias_mfma<1, 2><<<gg, 256, 0, stream>>>(
        key, nullptr, nullptr, Wkb, bk, nullptr, Kb, M, HID_C, HID_C, 1.f);
    // V^T: out[feat][token] = Wv @ value^T (A = Wv fp32, W-side = value bf16)
    dim3 gv(M / BN, HID_C / BM);             // (64, 8)
    gemm_xwt_bias_mfma<2, 2><<<gv, 256, 0, stream>>>(
        Wv, nullptr, nullptr, Vb, bv, nullptr, Vtg, HID_C, M, HID_C, 1.f);

    flash_attn_bf16<<<dim3((S_LEN / QBLK) * B * NHEADS), 256, 0, stream>>>(
        Qb, Kb, Vtg, Mb, Xhi, Xlo);

    gemm_xwt_bias_mfma<0, 1><<<gg, 256, 0, stream>>>(
        nullptr, Xhi, Xlo, Wob, bo, out, nullptr, M, HID_C, HID_C, 1.f);
}

// Round 10
// 282.062 us; speedup vs baseline: 1.6657x; 1.2446x over previous
//
#include <hip/hip_runtime.h>
#include <cstddef>
#include <math.h>

#define S_LEN  2048
#define HID_C  1024
#define NHEADS 16
#define HDIM   64

typedef __attribute__((ext_vector_type(8))) short bf16x8;
typedef __attribute__((ext_vector_type(4))) float f32x4;
typedef unsigned short ushort_t;

#define LOG2E 1.44269504088896f

// cheap round-to-nearest fp32 -> bf16 (ties-up; same 1/2-ulp bound as RNE)
__device__ __forceinline__ unsigned short f32_to_bf16_rn(float f) {
    unsigned int u = __float_as_uint(f);
    return (unsigned short)((u + 0x8000u) >> 16);
}

// ---------------------------------------------------------------------------
// prep: Wq/Wk/Wo -> bf16
// ---------------------------------------------------------------------------
__global__ void prep_w(const float* __restrict__ Wq, const float* __restrict__ Wk,
                       const float* __restrict__ Wo,
                       ushort_t* __restrict__ Wqb, ushort_t* __restrict__ Wkb,
                       ushort_t* __restrict__ Wob) {
    unsigned i = blockIdx.x * 256 + threadIdx.x;
    const unsigned NW = HID_C * HID_C;
    if (i < NW) { Wqb[i] = f32_to_bf16_rn(Wq[i]); return; }
    i -= NW;
    if (i < NW) { Wkb[i] = f32_to_bf16_rn(Wk[i]); return; }
    i -= NW;
    if (i < NW) { Wob[i] = f32_to_bf16_rn(Wo[i]); }
}

// ---------------------------------------------------------------------------
// scan: order-preserving compaction of valid key indices per batch.
// One wave per batch; ballot+popcount prefix. Deterministic.
// ---------------------------------------------------------------------------
__global__ void scan_mask(const int* __restrict__ mask, int* __restrict__ cidx,
                          int* __restrict__ nvalid, int* __restrict__ npads) {
    const int b = blockIdx.x;
    const int lane = threadIdx.x;           // blockDim.x == 64
    int base = 0;
    for (int i = 0; i < S_LEN / 64; ++i) {
        const int s = i * 64 + lane;
        const int v = mask[b * S_LEN + s];
        const unsigned long long bal = __ballot(v != 0);
        const int pre = __popcll(bal & ((1ull << lane) - 1ull));
        if (v) cidx[b * S_LEN + base + pre] = s;
        base += (int)__popcll(bal);
    }
    if (lane == 0) { nvalid[b] = base; npads[b] = (base + 63) & ~63; }
}

// ---------------------------------------------------------------------------
// gather: Kc[j] = bf16(key[cidx[j]]), Vc[j] = bf16(value[cidx[j]]) (compact,
// zero-padded to 128-multiple), Mbc[j] = 0 / -1e30 additive bias.
// One block per compact row (8192 blocks x 256 thr, 4 elems/thread).
// ---------------------------------------------------------------------------
__global__ void gather_kv(const float* __restrict__ key, const float* __restrict__ value,
                          const int* __restrict__ cidx, const int* __restrict__ nvalid,
                          ushort_t* __restrict__ Kc, ushort_t* __restrict__ Vc,
                          float* __restrict__ Mbc) {
    const int r = blockIdx.x;               // 0..8191
    const int b = r >> 11, j = r & 2047;
    const int tid = threadIdx.x;
    const int nv = nvalid[b];
    if (tid == 0) Mbc[r] = (j < nv) ? 0.f : -1e30f;
    const int np128 = (nv + 127) & ~127;
    if (j >= np128) return;
    uint2* kd = reinterpret_cast<uint2*>(Kc + (size_t)r * HID_C + tid * 4);
    uint2* vd = reinterpret_cast<uint2*>(Vc + (size_t)r * HID_C + tid * 4);
    if (j < nv) {
        const int src = cidx[b * S_LEN + j];
        const float4 kv = *reinterpret_cast<const float4*>(
            key + ((size_t)b * S_LEN + src) * HID_C + tid * 4);
        const float4 vv = *reinterpret_cast<const float4*>(
            value + ((size_t)b * S_LEN + src) * HID_C + tid * 4);
        uint2 kp, vp;
        kp.x = ((unsigned)f32_to_bf16_rn(kv.y) << 16) | f32_to_bf16_rn(kv.x);
        kp.y = ((unsigned)f32_to_bf16_rn(kv.w) << 16) | f32_to_bf16_rn(kv.z);
        vp.x = ((unsigned)f32_to_bf16_rn(vv.y) << 16) | f32_to_bf16_rn(vv.x);
        vp.y = ((unsigned)f32_to_bf16_rn(vv.w) << 16) | f32_to_bf16_rn(vv.z);
        *kd = kp; *vd = vp;
    } else {
        *kd = make_uint2(0u, 0u); *vd = make_uint2(0u, 0u);
    }
}

// ---------------------------------------------------------------------------
// MFMA GEMM: out[m,n] = (sum_k X[m,k]*W[n,k] + bias) * oscale
// W source always pre-rounded bf16 (Wb).
// AMODE 1: A = pre-split bf16 hi/lo (2 MFMA — fp32-out O-GEMM).
// AMODE 2: A = fp32, rounded in-kernel (1 MFMA).
// AMODE 3: A = pre-rounded bf16 (1 MFMA).
// OMODE 0: fp32 out, col bias. OMODE 1: bf16 out, col bias. OMODE 2: bf16 out, ROW bias.
// SKIP 0: none. SKIP 1: skip stripe if (bm&2047) >= npads[batch]. SKIP 2: same on bn.
// ---------------------------------------------------------------------------
#define BM 128
#define BN 128
#define BKg 32
#define LDKg 40

template <int OMODE, int AMODE, int SKIP>
__global__ __launch_bounds__(256) void gemm_xwt_bias_mfma(
    const float* __restrict__ Xf,
    const ushort_t* __restrict__ Xhi, const ushort_t* __restrict__ Xlo,
    const ushort_t* __restrict__ Wb, const float* __restrict__ bias,
    const int* __restrict__ npads,
    float* __restrict__ outF, ushort_t* __restrict__ outB,
    int M, int N, int K, float oscale)
{
    __shared__ __align__(16) short Ah[BM * LDKg];
    __shared__ __align__(16) short Al[(AMODE == 1) ? BM * LDKg : 8];
    __shared__ __align__(16) short Bh[BM * LDKg];

    const int tid  = threadIdx.x;
    const int lane = tid & 63;
    const int wave = tid >> 6;
    const int bm = blockIdx.y * BM;
    const int bn = blockIdx.x * BN;

    if (SKIP == 1) { if ((bm & 2047) >= npads[bm >> 11]) return; }
    if (SKIP == 2) { if ((bn & 2047) >= npads[bn >> 11]) return; }

    const int wm = (wave >> 1) * 64;
    const int wn = (wave & 1) * 64;
    const int sr = tid >> 1;
    const int sc = (tid & 1) * 16;

    f32x4 acc[4][4];
#pragma unroll
    for (int i = 0; i < 4; ++i)
#pragma unroll
        for (int j = 0; j < 4; ++j)
#pragma unroll
            for (int r = 0; r < 4; ++r) acc[i][j][r] = 0.f;

    const int fr = lane & 15;
    const int kb = (lane >> 4) * 8;

    for (int k0 = 0; k0 < K; k0 += BKg) {
        bf16x8 xr0, xr1, lr0, lr1;
        if (AMODE == 2) {
            const float* Xp = Xf + (size_t)(bm + sr) * K + sc + k0;
            float xv[16];
#pragma unroll
            for (int q = 0; q < 4; ++q) {
                float4 a = *reinterpret_cast<const float4*>(Xp + q * 4);
                xv[q*4+0]=a.x; xv[q*4+1]=a.y; xv[q*4+2]=a.z; xv[q*4+3]=a.w;
            }
            short xh[16];
#pragma unroll
            for (int j = 0; j < 16; ++j) xh[j] = (short)f32_to_bf16_rn(xv[j]);
            xr0 = *reinterpret_cast<bf16x8*>(&xh[0]);
            xr1 = *reinterpret_cast<bf16x8*>(&xh[8]);
        } else if (AMODE == 3) {
            const ushort_t* ap = Xhi + (size_t)(bm + sr) * K + sc + k0;
            xr0 = *reinterpret_cast<const bf16x8*>(ap);
            xr1 = *reinterpret_cast<const bf16x8*>(ap + 8);
        } else {
            const ushort_t* hp = Xhi + (size_t)(bm + sr) * K + sc + k0;
            const ushort_t* lp = Xlo + (size_t)(bm + sr) * K + sc + k0;
            xr0 = *reinterpret_cast<const bf16x8*>(hp);
            xr1 = *reinterpret_cast<const bf16x8*>(hp + 8);
            lr0 = *reinterpret_cast<const bf16x8*>(lp);
            lr1 = *reinterpret_cast<const bf16x8*>(lp + 8);
        }
        const ushort_t* wp = Wb + (size_t)(bn + sr) * K + sc + k0;
        bf16x8 wr0 = *reinterpret_cast<const bf16x8*>(wp);
        bf16x8 wr1 = *reinterpret_cast<const bf16x8*>(wp + 8);

        __syncthreads();
        const int wbase = sr * LDKg + sc;
        *reinterpret_cast<bf16x8*>(&Ah[wbase])     = xr0;
        *reinterpret_cast<bf16x8*>(&Ah[wbase + 8]) = xr1;
        if (AMODE == 1) {
            *reinterpret_cast<bf16x8*>(&Al[wbase])     = lr0;
            *reinterpret_cast<bf16x8*>(&Al[wbase + 8]) = lr1;
        }
        *reinterpret_cast<bf16x8*>(&Bh[wbase])     = wr0;
        *reinterpret_cast<bf16x8*>(&Bh[wbase + 8]) = wr1;
        __syncthreads();

        bf16x8 fah[4], fal[4], fbh[4];
#pragma unroll
        for (int mi = 0; mi < 4; ++mi) {
            const int ra = (wm + mi * 16 + fr) * LDKg + kb;
            fah[mi] = *reinterpret_cast<const bf16x8*>(&Ah[ra]);
            if (AMODE == 1) fal[mi] = *reinterpret_cast<const bf16x8*>(&Al[ra]);
        }
#pragma unroll
        for (int ni = 0; ni < 4; ++ni) {
            const int rb = (wn + ni * 16 + fr) * LDKg + kb;
            fbh[ni] = *reinterpret_cast<const bf16x8*>(&Bh[rb]);
        }

#pragma unroll
        for (int mi = 0; mi < 4; ++mi)
#pragma unroll
            for (int ni = 0; ni < 4; ++ni) {
                acc[mi][ni] = __builtin_amdgcn_mfma_f32_16x16x32_bf16(
                    fah[mi], fbh[ni], acc[mi][ni], 0, 0, 0);
                if (AMODE == 1)
                    acc[mi][ni] = __builtin_amdgcn_mfma_f32_16x16x32_bf16(
                        fal[mi], fbh[ni], acc[mi][ni], 0, 0, 0);
            }
    }

    const int fq = lane >> 4;
    if (OMODE == 2) {
#pragma unroll
        for (int mi = 0; mi < 4; ++mi) {
#pragma unroll
            for (int r = 0; r < 4; ++r) {
                const int row = bm + wm + mi * 16 + fq * 4 + r;
                const float bvr = bias[row];
#pragma unroll
                for (int ni = 0; ni < 4; ++ni) {
                    const int col = bn + wn + ni * 16 + fr;
                    outB[(size_t)row * N + col] =
                        f32_to_bf16_rn((acc[mi][ni][r] + bvr) * oscale);
                }
            }
        }
    } else {
        float bv[4];
#pragma unroll
        for (int ni = 0; ni < 4; ++ni) bv[ni] = bias[bn + wn + ni * 16 + fr];
#pragma unroll
        for (int mi = 0; mi < 4; ++mi)
#pragma unroll
            for (int ni = 0; ni < 4; ++ni) {
                const size_t rowb = (size_t)(bm + wm + mi * 16 + fq * 4);
                const int col = bn + wn + ni * 16 + fr;
#pragma unroll
                for (int r = 0; r < 4; ++r) {
                    float v = (acc[mi][ni][r] + bv[ni]) * oscale;
                    if (OMODE == 0) outF[(rowb + r) * N + col] = v;
                    else            outB[(rowb + r) * N + col] = f32_to_bf16_rn(v);
                }
            }
    }
}

// ---------------------------------------------------------------------------
// Flash attention over COMPACTED keys: loop bound npads[b] (valid keys only,
// 64-padded; pad cols have bias -1e30 -> P = 0 exactly). Otherwise R8/R9
// structure: swapped QK^T, XCD-affinity grid, exp2 softmax, defer-max,
// reg-prefetch, pre-split output.
// ---------------------------------------------------------------------------
#define QBLK 128
#define KVB  64
#define LDA  72

__global__ __launch_bounds__(256) void flash_attn_bf16(
    const ushort_t* __restrict__ Qb, const ushort_t* __restrict__ Kb,
    const ushort_t* __restrict__ Vtg, const float* __restrict__ maskb,
    const int* __restrict__ npads,
    ushort_t* __restrict__ Xhi, ushort_t* __restrict__ Xlo)
{
    __shared__ __align__(16) ushort_t Ks[KVB * LDA];
    __shared__ __align__(16) ushort_t Vt[HDIM * LDA];
    __shared__ __align__(16) ushort_t Ps[QBLK * LDA];
    __shared__ float XposeA[QBLK];

    const int n  = blockIdx.x;
    const int bh = (n & 7) * 8 + ((n >> 3) & 7);
    const int qx = n >> 6;
    const int b  = bh >> 4;
    const int h  = bh & 15;
    const int q0 = qx * QBLK;

    const int tid  = threadIdx.x;
    const int lane = tid & 63;
    const int w    = tid >> 6;
    const int fr = lane & 15;
    const int fq = lane >> 4;

    const size_t bS = (size_t)b * S_LEN;
    const int hc = h * HDIM;
    const int npad = npads[b];

    bf16x8 qf[2][2];
#pragma unroll
    for (int mt = 0; mt < 2; ++mt)
#pragma unroll
        for (int c = 0; c < 2; ++c)
            qf[mt][c] = *reinterpret_cast<const bf16x8*>(
                &Qb[(bS + q0 + w * 32 + mt * 16 + fr) * HID_C + hc + c * 32 + fq * 8]);

    f32x4 OV[2][4];
    float m_[2], l_[2];
#pragma unroll
    for (int mt = 0; mt < 2; ++mt) {
        m_[mt] = -1e30f; l_[mt] = 0.f;
#pragma unroll
        for (int dt = 0; dt < 4; ++dt)
#pragma unroll
            for (int r = 0; r < 4; ++r) OV[mt][dt][r] = 0.f;
    }

    const int sr  = tid >> 2;
    const int seg = tid & 3;
    const ushort_t* kbase = &Kb[(bS + sr) * HID_C + hc + seg * 16];
    const ushort_t* vbase = &Vtg[(size_t)(hc + sr) * (4 * S_LEN) + bS + seg * 16];

    {
        bf16x8 kv0 = *reinterpret_cast<const bf16x8*>(kbase);
        bf16x8 kv1 = *reinterpret_cast<const bf16x8*>(kbase + 8);
        bf16x8 vv0 = *reinterpret_cast<const bf16x8*>(vbase);
        bf16x8 vv1 = *reinterpret_cast<const bf16x8*>(vbase + 8);
        *reinterpret_cast<bf16x8*>(&Ks[sr * LDA + seg * 16])     = kv0;
        *reinterpret_cast<bf16x8*>(&Ks[sr * LDA + seg * 16 + 8]) = kv1;
        *reinterpret_cast<bf16x8*>(&Vt[sr * LDA + seg * 16])     = vv0;
        *reinterpret_cast<bf16x8*>(&Vt[sr * LDA + seg * 16 + 8]) = vv1;
        __syncthreads();
    }

    for (int t = 0; t < npad; t += KVB) {
        float4 mbv[4];
#pragma unroll
        for (int nt = 0; nt < 4; ++nt)
            mbv[nt] = *reinterpret_cast<const float4*>(&maskb[bS + t + nt * 16 + fq * 4]);

        f32x4 S[2][4];
#pragma unroll
        for (int mt = 0; mt < 2; ++mt)
#pragma unroll
            for (int nt = 0; nt < 4; ++nt)
#pragma unroll
                for (int r = 0; r < 4; ++r) S[mt][nt][r] = 0.f;

        __builtin_amdgcn_s_setprio(1);
#pragma unroll
        for (int nt = 0; nt < 4; ++nt)
#pragma unroll
            for (int c = 0; c < 2; ++c) {
                bf16x8 kf = *reinterpret_cast<const bf16x8*>(
                    &Ks[(nt * 16 + fr) * LDA + c * 32 + fq * 8]);
#pragma unroll
                for (int mt = 0; mt < 2; ++mt)
                    S[mt][nt] = __builtin_amdgcn_mfma_f32_16x16x32_bf16(
                        kf, qf[mt][c], S[mt][nt], 0, 0, 0);
            }
        __builtin_amdgcn_s_setprio(0);

        const bool more = (t + KVB < npad);
        bf16x8 kv0n, kv1n, vv0n, vv1n;
        if (more) {
            const ushort_t* kp = kbase + (size_t)(t + KVB) * HID_C;
            const ushort_t* vp = vbase + (t + KVB);
            kv0n = *reinterpret_cast<const bf16x8*>(kp);
            kv1n = *reinterpret_cast<const bf16x8*>(kp + 8);
            vv0n = *reinterpret_cast<const bf16x8*>(vp);
            vv1n = *reinterpret_cast<const bf16x8*>(vp + 8);
        }

        float mx[2];
        int okl = 1;
#pragma unroll
        for (int mt = 0; mt < 2; ++mt) {
#pragma unroll
            for (int nt = 0; nt < 4; ++nt)
#pragma unroll
                for (int r = 0; r < 4; ++r) S[mt][nt][r] += mbv[nt][r];
            float v0 = fmaxf(fmaxf(S[mt][0][0], S[mt][0][1]),
                             fmaxf(S[mt][0][2], S[mt][0][3]));
            float v1 = fmaxf(fmaxf(S[mt][1][0], S[mt][1][1]),
                             fmaxf(S[mt][1][2], S[mt][1][3]));
            float v2 = fmaxf(fmaxf(S[mt][2][0], S[mt][2][1]),
                             fmaxf(S[mt][2][2], S[mt][2][3]));
            float v3 = fmaxf(fmaxf(S[mt][3][0], S[mt][3][1]),
                             fmaxf(S[mt][3][2], S[mt][3][3]));
            float v = fmaxf(fmaxf(v0, v1), fmaxf(v2, v3));
            v = fmaxf(v, __shfl_xor(v, 16));
            v = fmaxf(v, __shfl_xor(v, 32));
            mx[mt] = v;
            okl &= (v <= m_[mt] + 8.f);
        }

        if (!__all(okl)) {
            float corr[2];
#pragma unroll
            for (int mt = 0; mt < 2; ++mt) {
                float mn = fmaxf(m_[mt], mx[mt]);
                corr[mt] = exp2f(m_[mt] - mn);
                m_[mt] = mn;
                l_[mt] *= corr[mt];
                if (fq == 0) XposeA[w * 32 + mt * 16 + fr] = corr[mt];
            }
#pragma unroll
            for (int mt2 = 0; mt2 < 2; ++mt2)
#pragma unroll
                for (int r = 0; r < 4; ++r) {
                    float cq = XposeA[w * 32 + mt2 * 16 + fq * 4 + r];
#pragma unroll
                    for (int dt = 0; dt < 4; ++dt) OV[mt2][dt][r] *= cq;
                }
        }

#pragma unroll
        for (int mt = 0; mt < 2; ++mt) {
            float ls = 0.f;
#pragma unroll
            for (int nt = 0; nt < 4; ++nt) {
                float p0 = exp2f(S[mt][nt][0] - m_[mt]);
                float p1 = exp2f(S[mt][nt][1] - m_[mt]);
                float p2 = exp2f(S[mt][nt][2] - m_[mt]);
                float p3 = exp2f(S[mt][nt][3] - m_[mt]);
                ls += (p0 + p1) + (p2 + p3);
                uint2 pk;
                pk.x = ((unsigned int)f32_to_bf16_rn(p1) << 16) | f32_to_bf16_rn(p0);
                pk.y = ((unsigned int)f32_to_bf16_rn(p3) << 16) | f32_to_bf16_rn(p2);
                *reinterpret_cast<uint2*>(
                    &Ps[(w * 32 + mt * 16 + fr) * LDA + nt * 16 + fq * 4]) = pk;
            }
            ls += __shfl_xor(ls, 16);
            ls += __shfl_xor(ls, 32);
            l_[mt] += ls;
        }

        bf16x8 pf[2][2];
#pragma unroll
        for (int mt = 0; mt < 2; ++mt)
#pragma unroll
            for (int c = 0; c < 2; ++c)
                pf[mt][c] = *reinterpret_cast<const bf16x8*>(
                    &Ps[(w * 32 + mt * 16 + fr) * LDA + c * 32 + fq * 8]);

        __builtin_amdgcn_s_setprio(1);
#pragma unroll
        for (int dt = 0; dt < 4; ++dt)
#pragma unroll
            for (int c = 0; c < 2; ++c) {
                bf16x8 vf = *reinterpret_cast<const bf16x8*>(
                    &Vt[(dt * 16 + fr) * LDA + c * 32 + fq * 8]);
#pragma unroll
                for (int mt = 0; mt < 2; ++mt)
                    OV[mt][dt] = __builtin_amdgcn_mfma_f32_16x16x32_bf16(
                        pf[mt][c], vf, OV[mt][dt], 0, 0, 0);
            }
        __builtin_amdgcn_s_setprio(0);

        __syncthreads();
        if (more) {
            *reinterpret_cast<bf16x8*>(&Ks[sr * LDA + seg * 16])     = kv0n;
            *reinterpret_cast<bf16x8*>(&Ks[sr * LDA + seg * 16 + 8]) = kv1n;
            *reinterpret_cast<bf16x8*>(&Vt[sr * LDA + seg * 16])     = vv0n;
            *reinterpret_cast<bf16x8*>(&Vt[sr * LDA + seg * 16 + 8]) = vv1n;
            __syncthreads();
        }
    }

    if (fq == 0) {
        XposeA[w * 32 + fr]      = 1.f / l_[0];
        XposeA[w * 32 + 16 + fr] = 1.f / l_[1];
    }
#pragma unroll
    for (int mt = 0; mt < 2; ++mt)
#pragma unroll
        for (int r = 0; r < 4; ++r) {
            const float inv = XposeA[w * 32 + mt * 16 + fq * 4 + r];
            const size_t row = bS + q0 + w * 32 + mt * 16 + fq * 4 + r;
#pragma unroll
            for (int dt = 0; dt < 4; ++dt) {
                float v = OV[mt][dt][r] * inv;
                unsigned int u = __float_as_uint(v);
                unsigned short hi = (unsigned short)(u >> 16);
                float res = v - __uint_as_float(u & 0xFFFF0000u);
                Xhi[row * HID_C + hc + dt * 16 + fr] = hi;
                Xlo[row * HID_C + hc + dt * 16 + fr] = f32_to_bf16_rn(res);
            }
        }
}

// ---------------------------------------------------------------------------
extern "C" void kernel_launch(void* const* d_in, const int* in_sizes, int n_in,
                              void* d_out, int out_size, void* d_ws, size_t ws_size,
                              hipStream_t stream) {
    const float* query = (const float*)d_in[0];
    const float* key   = (const float*)d_in[1];
    const float* value = (const float*)d_in[2];
    const int*   mask  = (const int*)d_in[3];
    const float* Wq = (const float*)d_in[4];
    const float* bq = (const float*)d_in[5];
    const float* Wk = (const float*)d_in[6];
    const float* bk = (const float*)d_in[7];
    const float* Wv = (const float*)d_in[8];
    const float* bv = (const float*)d_in[9];
    const float* Wo = (const float*)d_in[10];
    const float* bo = (const float*)d_in[11];
    float* out = (float*)d_out;

    const int B = 4, M = B * S_LEN;          // 8192
    const size_t seg = (size_t)M * HID_C;
    const size_t nw  = (size_t)HID_C * HID_C;

    ushort_t* Qb  = (ushort_t*)d_ws;         // 16MB each
    ushort_t* Kb  = Qb + seg;
    ushort_t* Vtg = Kb + seg;                // V^T: [1024 feat][8192 compact tok]
    ushort_t* Xhi = Vtg + seg;               // aliased: Kc before attn
    ushort_t* Xlo = Xhi + seg;               // aliased: Vc before attn
    float*    Mbc = (float*)(Xlo + seg);     // 32KB compact mask bias
    ushort_t* Wqb = (ushort_t*)(Mbc + 4 * S_LEN);
    ushort_t* Wkb = Wqb + nw;                // 2MB each
    ushort_t* Wob = Wkb + nw;
    int*      cidx   = (int*)(Wob + nw);     // 32KB
    int*      nvalid = cidx + 4 * S_LEN;
    int*      npads  = nvalid + 4;

    ushort_t* Kc = Xhi;                      // compact bf16 key rows
    ushort_t* Vc = Xlo;                      // compact bf16 value rows

    prep_w<<<dim3((3u * (unsigned)nw + 255) / 256), 256, 0, stream>>>(
        Wq, Wk, Wo, Wqb, Wkb, Wob);
    scan_mask<<<dim3(4), 64, 0, stream>>>(mask, cidx, nvalid, npads);
    gather_kv<<<dim3(M), 256, 0, stream>>>(key, value, cidx, nvalid, Kc, Vc, Mbc);

    const float SC2 = 0.125f * LOG2E;
    dim3 gg(HID_C / BN, M / BM);             // (8, 64)
    gemm_xwt_bias_mfma<1, 2, 0><<<gg, 256, 0, stream>>>(
        query, nullptr, nullptr, Wqb, bq, npads, nullptr, Qb, M, HID_C, HID_C, SC2);
    gemm_xwt_bias_mfma<1, 3, 1><<<gg, 256, 0, stream>>>(
        nullptr, Kc, nullptr, Wkb, bk, npads, nullptr, Kb, M, HID_C, HID_C, 1.f);
    // V^T: out[feat][tok] = Wv @ Vc^T (row bias), token stripes early-exit
    dim3 gv(M / BN, HID_C / BM);             // (64, 8)
    gemm_xwt_bias_mfma<2, 2, 2><<<gv, 256, 0, stream>>>(
        Wv, nullptr, nullptr, Vc, bv, npads, nullptr, Vtg, HID_C, M, HID_C, 1.f);

    flash_attn_bf16<<<dim3((S_LEN / QBLK) * B * NHEADS), 256, 0, stream>>>(
        Qb, Kb, Vtg, Mbc, npads, Xhi, Xlo);

    gemm_xwt_bias_mfma<0, 1, 0><<<gg, 256, 0, stream>>>(
        nullptr, Xhi, Xlo, Wob, bo, npads, out, nullptr, M, HID_C, HID_C, 1.f);
}

// Round 11
// 267.702 us; speedup vs baseline: 1.7551x; 1.0536x over previous
//
#include <hip/hip_runtime.h>
#include <cstddef>
#include <math.h>

#define S_LEN  2048
#define HID_C  1024
#define NHEADS 16
#define HDIM   64

typedef __attribute__((ext_vector_type(8))) short bf16x8;
typedef __attribute__((ext_vector_type(4))) float f32x4;
typedef __attribute__((ext_vector_type(16))) float f32x16;
typedef unsigned short ushort_t;

#define LOG2E 1.44269504088896f

// cheap round-to-nearest fp32 -> bf16 (ties-up; same 1/2-ulp bound as RNE)
__device__ __forceinline__ unsigned short f32_to_bf16_rn(float f) {
    unsigned int u = __float_as_uint(f);
    return (unsigned short)((u + 0x8000u) >> 16);
}

// ---------------------------------------------------------------------------
// prep: Wq/Wk/Wo -> bf16
// ---------------------------------------------------------------------------
__global__ void prep_w(const float* __restrict__ Wq, const float* __restrict__ Wk,
                       const float* __restrict__ Wo,
                       ushort_t* __restrict__ Wqb, ushort_t* __restrict__ Wkb,
                       ushort_t* __restrict__ Wob) {
    unsigned i = blockIdx.x * 256 + threadIdx.x;
    const unsigned NW = HID_C * HID_C;
    if (i < NW) { Wqb[i] = f32_to_bf16_rn(Wq[i]); return; }
    i -= NW;
    if (i < NW) { Wkb[i] = f32_to_bf16_rn(Wk[i]); return; }
    i -= NW;
    if (i < NW) { Wob[i] = f32_to_bf16_rn(Wo[i]); }
}

// ---------------------------------------------------------------------------
// scan: order-preserving compaction of valid key indices per batch.
// ---------------------------------------------------------------------------
__global__ void scan_mask(const int* __restrict__ mask, int* __restrict__ cidx,
                          int* __restrict__ nvalid, int* __restrict__ npads) {
    const int b = blockIdx.x;
    const int lane = threadIdx.x;           // blockDim.x == 64
    int base = 0;
    for (int i = 0; i < S_LEN / 64; ++i) {
        const int s = i * 64 + lane;
        const int v = mask[b * S_LEN + s];
        const unsigned long long bal = __ballot(v != 0);
        const int pre = __popcll(bal & ((1ull << lane) - 1ull));
        if (v) cidx[b * S_LEN + base + pre] = s;
        base += (int)__popcll(bal);
    }
    if (lane == 0) { nvalid[b] = base; npads[b] = (base + 63) & ~63; }
}

// ---------------------------------------------------------------------------
// gather: compact bf16 key/value rows (zero-padded to 128), compact mask bias.
// ---------------------------------------------------------------------------
__global__ void gather_kv(const float* __restrict__ key, const float* __restrict__ value,
                          const int* __restrict__ cidx, const int* __restrict__ nvalid,
                          ushort_t* __restrict__ Kc, ushort_t* __restrict__ Vc,
                          float* __restrict__ Mbc) {
    const int r = blockIdx.x;               // 0..8191
    const int b = r >> 11, j = r & 2047;
    const int tid = threadIdx.x;
    const int nv = nvalid[b];
    if (tid == 0) Mbc[r] = (j < nv) ? 0.f : -1e30f;
    const int np128 = (nv + 127) & ~127;
    if (j >= np128) return;
    uint2* kd = reinterpret_cast<uint2*>(Kc + (size_t)r * HID_C + tid * 4);
    uint2* vd = reinterpret_cast<uint2*>(Vc + (size_t)r * HID_C + tid * 4);
    if (j < nv) {
        const int src = cidx[b * S_LEN + j];
        const float4 kv = *reinterpret_cast<const float4*>(
            key + ((size_t)b * S_LEN + src) * HID_C + tid * 4);
        const float4 vv = *reinterpret_cast<const float4*>(
            value + ((size_t)b * S_LEN + src) * HID_C + tid * 4);
        uint2 kp, vp;
        kp.x = ((unsigned)f32_to_bf16_rn(kv.y) << 16) | f32_to_bf16_rn(kv.x);
        kp.y = ((unsigned)f32_to_bf16_rn(kv.w) << 16) | f32_to_bf16_rn(kv.z);
        vp.x = ((unsigned)f32_to_bf16_rn(vv.y) << 16) | f32_to_bf16_rn(vv.x);
        vp.y = ((unsigned)f32_to_bf16_rn(vv.w) << 16) | f32_to_bf16_rn(vv.z);
        *kd = kp; *vd = vp;
    } else {
        *kd = make_uint2(0u, 0u); *vd = make_uint2(0u, 0u);
    }
}

// ---------------------------------------------------------------------------
// MFMA GEMM (unchanged from R10): out[m,n] = (sum_k X[m,k]*W[n,k] + bias)*oscale
// AMODE 1: pre-split hi/lo (2 MFMA). AMODE 2: fp32->bf16 in-kernel. AMODE 3: bf16.
// OMODE 0: fp32/col. OMODE 1: bf16/col. OMODE 2: bf16/ROW bias.
// SKIP 1: early-exit m-stripes >= npads. SKIP 2: same on n.
// ---------------------------------------------------------------------------
#define BM 128
#define BN 128
#define BKg 32
#define LDKg 40

template <int OMODE, int AMODE, int SKIP>
__global__ __launch_bounds__(256) void gemm_xwt_bias_mfma(
    const float* __restrict__ Xf,
    const ushort_t* __restrict__ Xhi, const ushort_t* __restrict__ Xlo,
    const ushort_t* __restrict__ Wb, const float* __restrict__ bias,
    const int* __restrict__ npads,
    float* __restrict__ outF, ushort_t* __restrict__ outB,
    int M, int N, int K, float oscale)
{
    __shared__ __align__(16) short Ah[BM * LDKg];
    __shared__ __align__(16) short Al[(AMODE == 1) ? BM * LDKg : 8];
    __shared__ __align__(16) short Bh[BM * LDKg];

    const int tid  = threadIdx.x;
    const int lane = tid & 63;
    const int wave = tid >> 6;
    const int bm = blockIdx.y * BM;
    const int bn = blockIdx.x * BN;

    if (SKIP == 1) { if ((bm & 2047) >= npads[bm >> 11]) return; }
    if (SKIP == 2) { if ((bn & 2047) >= npads[bn >> 11]) return; }

    const int wm = (wave >> 1) * 64;
    const int wn = (wave & 1) * 64;
    const int sr = tid >> 1;
    const int sc = (tid & 1) * 16;

    f32x4 acc[4][4];
#pragma unroll
    for (int i = 0; i < 4; ++i)
#pragma unroll
        for (int j = 0; j < 4; ++j)
#pragma unroll
            for (int r = 0; r < 4; ++r) acc[i][j][r] = 0.f;

    const int fr = lane & 15;
    const int kb = (lane >> 4) * 8;

    for (int k0 = 0; k0 < K; k0 += BKg) {
        bf16x8 xr0, xr1, lr0, lr1;
        if (AMODE == 2) {
            const float* Xp = Xf + (size_t)(bm + sr) * K + sc + k0;
            float xv[16];
#pragma unroll
            for (int q = 0; q < 4; ++q) {
                float4 a = *reinterpret_cast<const float4*>(Xp + q * 4);
                xv[q*4+0]=a.x; xv[q*4+1]=a.y; xv[q*4+2]=a.z; xv[q*4+3]=a.w;
            }
            short xh[16];
#pragma unroll
            for (int j = 0; j < 16; ++j) xh[j] = (short)f32_to_bf16_rn(xv[j]);
            xr0 = *reinterpret_cast<bf16x8*>(&xh[0]);
            xr1 = *reinterpret_cast<bf16x8*>(&xh[8]);
        } else if (AMODE == 3) {
            const ushort_t* ap = Xhi + (size_t)(bm + sr) * K + sc + k0;
            xr0 = *reinterpret_cast<const bf16x8*>(ap);
            xr1 = *reinterpret_cast<const bf16x8*>(ap + 8);
        } else {
            const ushort_t* hp = Xhi + (size_t)(bm + sr) * K + sc + k0;
            const ushort_t* lp = Xlo + (size_t)(bm + sr) * K + sc + k0;
            xr0 = *reinterpret_cast<const bf16x8*>(hp);
            xr1 = *reinterpret_cast<const bf16x8*>(hp + 8);
            lr0 = *reinterpret_cast<const bf16x8*>(lp);
            lr1 = *reinterpret_cast<const bf16x8*>(lp + 8);
        }
        const ushort_t* wp = Wb + (size_t)(bn + sr) * K + sc + k0;
        bf16x8 wr0 = *reinterpret_cast<const bf16x8*>(wp);
        bf16x8 wr1 = *reinterpret_cast<const bf16x8*>(wp + 8);

        __syncthreads();
        const int wbase = sr * LDKg + sc;
        *reinterpret_cast<bf16x8*>(&Ah[wbase])     = xr0;
        *reinterpret_cast<bf16x8*>(&Ah[wbase + 8]) = xr1;
        if (AMODE == 1) {
            *reinterpret_cast<bf16x8*>(&Al[wbase])     = lr0;
            *reinterpret_cast<bf16x8*>(&Al[wbase + 8]) = lr1;
        }
        *reinterpret_cast<bf16x8*>(&Bh[wbase])     = wr0;
        *reinterpret_cast<bf16x8*>(&Bh[wbase + 8]) = wr1;
        __syncthreads();

        bf16x8 fah[4], fal[4], fbh[4];
#pragma unroll
        for (int mi = 0; mi < 4; ++mi) {
            const int ra = (wm + mi * 16 + fr) * LDKg + kb;
            fah[mi] = *reinterpret_cast<const bf16x8*>(&Ah[ra]);
            if (AMODE == 1) fal[mi] = *reinterpret_cast<const bf16x8*>(&Al[ra]);
        }
#pragma unroll
        for (int ni = 0; ni < 4; ++ni) {
            const int rb = (wn + ni * 16 + fr) * LDKg + kb;
            fbh[ni] = *reinterpret_cast<const bf16x8*>(&Bh[rb]);
        }

#pragma unroll
        for (int mi = 0; mi < 4; ++mi)
#pragma unroll
            for (int ni = 0; ni < 4; ++ni) {
                acc[mi][ni] = __builtin_amdgcn_mfma_f32_16x16x32_bf16(
                    fah[mi], fbh[ni], acc[mi][ni], 0, 0, 0);
                if (AMODE == 1)
                    acc[mi][ni] = __builtin_amdgcn_mfma_f32_16x16x32_bf16(
                        fal[mi], fbh[ni], acc[mi][ni], 0, 0, 0);
            }
    }

    const int fq = lane >> 4;
    if (OMODE == 2) {
#pragma unroll
        for (int mi = 0; mi < 4; ++mi) {
#pragma unroll
            for (int r = 0; r < 4; ++r) {
                const int row = bm + wm + mi * 16 + fq * 4 + r;
                const float bvr = bias[row];
#pragma unroll
                for (int ni = 0; ni < 4; ++ni) {
                    const int col = bn + wn + ni * 16 + fr;
                    outB[(size_t)row * N + col] =
                        f32_to_bf16_rn((acc[mi][ni][r] + bvr) * oscale);
                }
            }
        }
    } else {
        float bv[4];
#pragma unroll
        for (int ni = 0; ni < 4; ++ni) bv[ni] = bias[bn + wn + ni * 16 + fr];
#pragma unroll
        for (int mi = 0; mi < 4; ++mi)
#pragma unroll
            for (int ni = 0; ni < 4; ++ni) {
                const size_t rowb = (size_t)(bm + wm + mi * 16 + fq * 4);
                const int col = bn + wn + ni * 16 + fr;
#pragma unroll
                for (int r = 0; r < 4; ++r) {
                    float v = (acc[mi][ni][r] + bv[ni]) * oscale;
                    if (OMODE == 0) outF[(rowb + r) * N + col] = v;
                    else            outB[(rowb + r) * N + col] = f32_to_bf16_rn(v);
                }
            }
    }
}

// ---------------------------------------------------------------------------
// Flash attention, 32x32 MFMA + fully in-register P (T12).
// Swapped QK^T with mfma_f32_32x32x16: S = mfma(K, Q) -> C[row=k, col=q], so
// lane l owns q = l&31 and 16 k-regs per 32-k tile (row = (r&3)+8*(r>>2)+4*(l>>5)).
// Softmax: in-register reduce + ONE shfl_xor(32). P -> PV A-frags via
// v_cvt_pk_bf16_f32 + v_permlane32_swap_b32 (no LDS round-trip).
// Compacted keys (loop bound npads[b]); XCD-affinity grid; defer-max.
// ---------------------------------------------------------------------------
#define QBLK 128
#define KVB  64
#define LDA  72

__global__ __launch_bounds__(256) void flash_attn_bf16(
    const ushort_t* __restrict__ Qb, const ushort_t* __restrict__ Kb,
    const ushort_t* __restrict__ Vtg, const float* __restrict__ maskb,
    const int* __restrict__ npads,
    ushort_t* __restrict__ Xhi, ushort_t* __restrict__ Xlo)
{
    __shared__ __align__(16) ushort_t Ks[KVB * LDA];   // [k 0..63][d 0..63]
    __shared__ __align__(16) ushort_t Vt[HDIM * LDA];  // [d 0..63][tok 0..63]
    __shared__ float Xpose[QBLK];

    const int n  = blockIdx.x;
    const int bh = (n & 7) * 8 + ((n >> 3) & 7);
    const int qx = n >> 6;
    const int b  = bh >> 4;
    const int h  = bh & 15;
    const int q0 = qx * QBLK;

    const int tid  = threadIdx.x;
    const int lane = tid & 63;
    const int w    = tid >> 6;
    const int lq = lane & 31;   // q column (and frag row/col id)
    const int lh = lane >> 5;   // half: k-dim sub-offset

    const size_t bS = (size_t)b * S_LEN;
    const int hc = h * HDIM;
    const int npad = npads[b];

    // Q fragments: B-operand, col = q = w*32+lq, k-dim d = s*16 + lh*8
    bf16x8 qf[4];
#pragma unroll
    for (int s = 0; s < 4; ++s)
        qf[s] = *reinterpret_cast<const bf16x8*>(
            &Qb[(bS + q0 + w * 32 + lq) * HID_C + hc + s * 16 + lh * 8]);

    f32x16 OV[2];
#pragma unroll
    for (int dt = 0; dt < 2; ++dt)
#pragma unroll
        for (int r = 0; r < 16; ++r) OV[dt][r] = 0.f;
    float m_ = -1e30f, l_ = 0.f;

    const int sr  = tid >> 2;
    const int seg = tid & 3;
    const ushort_t* kbase = &Kb[(bS + sr) * HID_C + hc + seg * 16];
    const ushort_t* vbase = &Vtg[(size_t)(hc + sr) * (4 * S_LEN) + bS + seg * 16];

    // prologue: stage tile t=0
    {
        bf16x8 kv0 = *reinterpret_cast<const bf16x8*>(kbase);
        bf16x8 kv1 = *reinterpret_cast<const bf16x8*>(kbase + 8);
        bf16x8 vv0 = *reinterpret_cast<const bf16x8*>(vbase);
        bf16x8 vv1 = *reinterpret_cast<const bf16x8*>(vbase + 8);
        *reinterpret_cast<bf16x8*>(&Ks[sr * LDA + seg * 16])     = kv0;
        *reinterpret_cast<bf16x8*>(&Ks[sr * LDA + seg * 16 + 8]) = kv1;
        *reinterpret_cast<bf16x8*>(&Vt[sr * LDA + seg * 16])     = vv0;
        *reinterpret_cast<bf16x8*>(&Vt[sr * LDA + seg * 16 + 8]) = vv1;
        __syncthreads();
    }

    for (int t = 0; t < npad; t += KVB) {
        // mask bias: S[kt][r] needs k = t + kt*32 + (r&3) + 8*(r>>2) + 4*lh
        float4 mb[2][4];
#pragma unroll
        for (int kt = 0; kt < 2; ++kt)
#pragma unroll
            for (int g = 0; g < 4; ++g)
                mb[kt][g] = *reinterpret_cast<const float4*>(
                    &maskb[bS + t + kt * 32 + g * 8 + lh * 4]);

        // ---- QK^T (swapped, 32x32x16): S[kt] over d-steps s ----
        f32x16 S[2];
#pragma unroll
        for (int kt = 0; kt < 2; ++kt)
#pragma unroll
            for (int r = 0; r < 16; ++r) S[kt][r] = 0.f;

        __builtin_amdgcn_s_setprio(1);
#pragma unroll
        for (int kt = 0; kt < 2; ++kt)
#pragma unroll
            for (int s = 0; s < 4; ++s) {
                bf16x8 kf = *reinterpret_cast<const bf16x8*>(
                    &Ks[(kt * 32 + lq) * LDA + s * 16 + lh * 8]);
                S[kt] = __builtin_amdgcn_mfma_f32_32x32x16_bf16(
                    kf, qf[s], S[kt], 0, 0, 0);
            }
        __builtin_amdgcn_s_setprio(0);

        // ---- T14: issue next-tile K/V loads ----
        const bool more = (t + KVB < npad);
        bf16x8 kv0n, kv1n, vv0n, vv1n;
        if (more) {
            const ushort_t* kp = kbase + (size_t)(t + KVB) * HID_C;
            const ushort_t* vp = vbase + (t + KVB);
            kv0n = *reinterpret_cast<const bf16x8*>(kp);
            kv1n = *reinterpret_cast<const bf16x8*>(kp + 8);
            vv0n = *reinterpret_cast<const bf16x8*>(vp);
            vv1n = *reinterpret_cast<const bf16x8*>(vp + 8);
        }

        // ---- mask add + in-register row max (one q per lane) ----
        float mx = -1e30f;
#pragma unroll
        for (int kt = 0; kt < 2; ++kt)
#pragma unroll
            for (int r = 0; r < 16; ++r) {
                float sv = S[kt][r] +
                    reinterpret_cast<const float*>(&mb[kt][r >> 2])[r & 3];
                S[kt][r] = sv;
                mx = fmaxf(mx, sv);
            }
        mx = fmaxf(mx, __shfl_xor(mx, 32));

        // ---- defer-max (rare rescale) ----
        if (!__all(mx <= m_ + 8.f)) {
            float mn = fmaxf(m_, mx);
            float corr = exp2f(m_ - mn);
            m_ = mn; l_ *= corr;
            if (lh == 0) Xpose[w * 32 + lq] = corr;   // same-wave RAW
#pragma unroll
            for (int r = 0; r < 16; ++r) {
                float cq = Xpose[w * 32 + (r & 3) + 8 * (r >> 2) + 4 * lh];
                OV[0][r] *= cq;
                OV[1][r] *= cq;
            }
        }

        // ---- P = exp2(S - m), in-register row sum ----
        float ls = 0.f;
#pragma unroll
        for (int kt = 0; kt < 2; ++kt)
#pragma unroll
            for (int r = 0; r < 16; ++r) {
                float p = exp2f(S[kt][r] - m_);
                S[kt][r] = p;
                ls += p;
            }
        ls += __shfl_xor(ls, 32);
        l_ += ls;

        // ---- P -> PV A-frags in registers (cvt_pk + permlane32_swap) ----
        // frag f = kt*2+u covers kdot = f*16 + lh*8 + 0..7 for this lane.
        bf16x8 pa[4];
#pragma unroll
        for (int kt = 0; kt < 2; ++kt)
#pragma unroll
            for (int u = 0; u < 2; ++u) {
                const int bb = u * 8;
                unsigned int c0, c1, c2, c3;
                asm("v_cvt_pk_bf16_f32 %0, %1, %2"
                    : "=v"(c0) : "v"(S[kt][bb + 0]), "v"(S[kt][bb + 1]));
                asm("v_cvt_pk_bf16_f32 %0, %1, %2"
                    : "=v"(c1) : "v"(S[kt][bb + 2]), "v"(S[kt][bb + 3]));
                asm("v_cvt_pk_bf16_f32 %0, %1, %2"
                    : "=v"(c2) : "v"(S[kt][bb + 4]), "v"(S[kt][bb + 5]));
                asm("v_cvt_pk_bf16_f32 %0, %1, %2"
                    : "=v"(c3) : "v"(S[kt][bb + 6]), "v"(S[kt][bb + 7]));
                // swap low halves across lane 32 boundary:
                // after: c0 = W0, c2 = W2 ; c1 = W1, c3 = W3
                asm("v_permlane32_swap_b32 %0, %1" : "+v"(c0), "+v"(c2));
                asm("v_permlane32_swap_b32 %0, %1" : "+v"(c1), "+v"(c3));
                uint4 wv = make_uint4(c0, c1, c2, c3);
                pa[kt * 2 + u] = *reinterpret_cast<bf16x8*>(&wv);
            }

        // ---- PV (32x32x16): OV[dt] over 4 k-steps ----
        __builtin_amdgcn_s_setprio(1);
#pragma unroll
        for (int dt = 0; dt < 2; ++dt)
#pragma unroll
            for (int f = 0; f < 4; ++f) {
                bf16x8 vf = *reinterpret_cast<const bf16x8*>(
                    &Vt[(dt * 32 + lq) * LDA + f * 16 + lh * 8]);
                OV[dt] = __builtin_amdgcn_mfma_f32_32x32x16_bf16(
                    pa[f], vf, OV[dt], 0, 0, 0);
            }
        __builtin_amdgcn_s_setprio(0);

        // ---- stage next tile ----
        __syncthreads();
        if (more) {
            *reinterpret_cast<bf16x8*>(&Ks[sr * LDA + seg * 16])     = kv0n;
            *reinterpret_cast<bf16x8*>(&Ks[sr * LDA + seg * 16 + 8]) = kv1n;
            *reinterpret_cast<bf16x8*>(&Vt[sr * LDA + seg * 16])     = vv0n;
            *reinterpret_cast<bf16x8*>(&Vt[sr * LDA + seg * 16 + 8]) = vv1n;
            __syncthreads();
        }
    }

    // ---- epilogue: x = OV/l, pre-split hi/lo bf16 ----
    if (lh == 0) Xpose[w * 32 + lq] = 1.f / l_;   // same-wave RAW
#pragma unroll
    for (int r = 0; r < 16; ++r) {
        const int qr = (r & 3) + 8 * (r >> 2) + 4 * lh;
        const float inv = Xpose[w * 32 + qr];
        const size_t row = bS + q0 + w * 32 + qr;
#pragma unroll
        for (int dt = 0; dt < 2; ++dt) {
            float v = OV[dt][r] * inv;
            unsigned int u = __float_as_uint(v);
            unsigned short hi = (unsigned short)(u >> 16);
            float res = v - __uint_as_float(u & 0xFFFF0000u);
            Xhi[row * HID_C + hc + dt * 32 + lq] = hi;
            Xlo[row * HID_C + hc + dt * 32 + lq] = f32_to_bf16_rn(res);
        }
    }
}

// ---------------------------------------------------------------------------
extern "C" void kernel_launch(void* const* d_in, const int* in_sizes, int n_in,
                              void* d_out, int out_size, void* d_ws, size_t ws_size,
                              hipStream_t stream) {
    const float* query = (const float*)d_in[0];
    const float* key   = (const float*)d_in[1];
    const float* value = (const float*)d_in[2];
    const int*   mask  = (const int*)d_in[3];
    const float* Wq = (const float*)d_in[4];
    const float* bq = (const float*)d_in[5];
    const float* Wk = (const float*)d_in[6];
    const float* bk = (const float*)d_in[7];
    const float* Wv = (const float*)d_in[8];
    const float* bv = (const float*)d_in[9];
    const float* Wo = (const float*)d_in[10];
    const float* bo = (const float*)d_in[11];
    float* out = (float*)d_out;

    const int B = 4, M = B * S_LEN;          // 8192
    const size_t seg = (size_t)M * HID_C;
    const size_t nw  = (size_t)HID_C * HID_C;

    ushort_t* Qb  = (ushort_t*)d_ws;         // 16MB each
    ushort_t* Kb  = Qb + seg;
    ushort_t* Vtg = Kb + seg;                // V^T: [1024 feat][8192 compact tok]
    ushort_t* Xhi = Vtg + seg;               // aliased: Kc before attn
    ushort_t* Xlo = Xhi + seg;               // aliased: Vc before attn
    float*    Mbc = (float*)(Xlo + seg);     // 32KB compact mask bias
    ushort_t* Wqb = (ushort_t*)(Mbc + 4 * S_LEN);
    ushort_t* Wkb = Wqb + nw;                // 2MB each
    ushort_t* Wob = Wkb + nw;
    int*      cidx   = (int*)(Wob + nw);     // 32KB
    int*      nvalid = cidx + 4 * S_LEN;
    int*      npads  = nvalid + 4;

    ushort_t* Kc = Xhi;                      // compact bf16 key rows
    ushort_t* Vc = Xlo;                      // compact bf16 value rows

    prep_w<<<dim3((3u * (unsigned)nw + 255) / 256), 256, 0, stream>>>(
        Wq, Wk, Wo, Wqb, Wkb, Wob);
    scan_mask<<<dim3(4), 64, 0, stream>>>(mask, cidx, nvalid, npads);
    gather_kv<<<dim3(M), 256, 0, stream>>>(key, value, cidx, nvalid, Kc, Vc, Mbc);

    const float SC2 = 0.125f * LOG2E;
    dim3 gg(HID_C / BN, M / BM);             // (8, 64)
    gemm_xwt_bias_mfma<1, 2, 0><<<gg, 256, 0, stream>>>(
        query, nullptr, nullptr, Wqb, bq, npads, nullptr, Qb, M, HID_C, HID_C, SC2);
    gemm_xwt_bias_mfma<1, 3, 1><<<gg, 256, 0, stream>>>(
        nullptr, Kc, nullptr, Wkb, bk, npads, nullptr, Kb, M, HID_C, HID_C, 1.f);
    dim3 gv(M / BN, HID_C / BM);             // (64, 8)
    gemm_xwt_bias_mfma<2, 2, 2><<<gv, 256, 0, stream>>>(
        Wv, nullptr, nullptr, Vc, bv, npads, nullptr, Vtg, HID_C, M, HID_C, 1.f);

    flash_attn_bf16<<<dim3((S_LEN / QBLK) * B * NHEADS), 256, 0, stream>>>(
        Qb, Kb, Vtg, Mbc, npads, Xhi, Xlo);

    gemm_xwt_bias_mfma<0, 1, 0><<<gg, 256, 0, stream>>>(
        nullptr, Xhi, Xlo, Wob, bo, npads, out, nullptr, M, HID_C, HID_C, 1.f);
}

// Round 12
// 243.782 us; speedup vs baseline: 1.9273x; 1.0981x over previous
//
#include <hip/hip_runtime.h>
#include <cstddef>
#include <math.h>

#define S_LEN  2048
#define HID_C  1024
#define NHEADS 16
#define HDIM   64

typedef __attribute__((ext_vector_type(8))) short bf16x8;
typedef __attribute__((ext_vector_type(4))) float f32x4;
typedef __attribute__((ext_vector_type(16))) float f32x16;
typedef unsigned short ushort_t;

#define LOG2E 1.44269504088896f

// cheap round-to-nearest fp32 -> bf16 (ties-up; same 1/2-ulp bound as RNE)
__device__ __forceinline__ unsigned short f32_to_bf16_rn(float f) {
    unsigned int u = __float_as_uint(f);
    return (unsigned short)((u + 0x8000u) >> 16);
}

// direct global->LDS 16B copy (lds dest = wave-uniform base + lane*16)
__device__ __forceinline__ void gload16(const ushort_t* g, ushort_t* l) {
    __builtin_amdgcn_global_load_lds(
        (const __attribute__((address_space(1))) void*)g,
        (__attribute__((address_space(3))) void*)l, 16, 0, 0);
}

// ---------------------------------------------------------------------------
// prep: query -> bf16, Wq/Wk/Wo/Wv -> bf16 (vectorized 4/thread)
// ---------------------------------------------------------------------------
__global__ void prep_conv(const float* __restrict__ query,
                          const float* __restrict__ Wq, const float* __restrict__ Wk,
                          const float* __restrict__ Wo, const float* __restrict__ Wv,
                          ushort_t* __restrict__ Qbf, ushort_t* __restrict__ Wqb,
                          ushort_t* __restrict__ Wkb, ushort_t* __restrict__ Wob,
                          ushort_t* __restrict__ Wvb) {
    const unsigned SEG = 4u * S_LEN * HID_C;
    const unsigned NW = HID_C * HID_C;
    unsigned i = (blockIdx.x * 256u + threadIdx.x) * 4u;
    const float* src; ushort_t* dst;
    if (i < SEG) { src = query; dst = Qbf; }
    else {
        i -= SEG;
        if (i < NW) { src = Wq; dst = Wqb; }
        else { i -= NW;
            if (i < NW) { src = Wk; dst = Wkb; }
            else { i -= NW;
                if (i < NW) { src = Wo; dst = Wob; }
                else { i -= NW; if (i >= NW) return; src = Wv; dst = Wvb; }
            }
        }
    }
    float4 v = *reinterpret_cast<const float4*>(src + i);
    uint2 p;
    p.x = ((unsigned)f32_to_bf16_rn(v.y) << 16) | f32_to_bf16_rn(v.x);
    p.y = ((unsigned)f32_to_bf16_rn(v.w) << 16) | f32_to_bf16_rn(v.z);
    *reinterpret_cast<uint2*>(dst + i) = p;
}

// ---------------------------------------------------------------------------
// scan: order-preserving compaction of valid key indices per batch.
// ---------------------------------------------------------------------------
__global__ void scan_mask(const int* __restrict__ mask, int* __restrict__ cidx,
                          int* __restrict__ nvalid, int* __restrict__ npads) {
    const int b = blockIdx.x;
    const int lane = threadIdx.x;           // blockDim.x == 64
    int base = 0;
    for (int i = 0; i < S_LEN / 64; ++i) {
        const int s = i * 64 + lane;
        const int v = mask[b * S_LEN + s];
        const unsigned long long bal = __ballot(v != 0);
        const int pre = __popcll(bal & ((1ull << lane) - 1ull));
        if (v) cidx[b * S_LEN + base + pre] = s;
        base += (int)__popcll(bal);
    }
    if (lane == 0) { nvalid[b] = base; npads[b] = (base + 63) & ~63; }
}

// ---------------------------------------------------------------------------
// gather: compact bf16 key/value rows (zero-padded to 128), compact mask bias.
// ---------------------------------------------------------------------------
__global__ void gather_kv(const float* __restrict__ key, const float* __restrict__ value,
                          const int* __restrict__ cidx, const int* __restrict__ nvalid,
                          ushort_t* __restrict__ Kc, ushort_t* __restrict__ Vc,
                          float* __restrict__ Mbc) {
    const int r = blockIdx.x;               // 0..8191
    const int b = r >> 11, j = r & 2047;
    const int tid = threadIdx.x;
    const int nv = nvalid[b];
    if (tid == 0) Mbc[r] = (j < nv) ? 0.f : -1e30f;
    const int np128 = (nv + 127) & ~127;
    if (j >= np128) return;
    uint2* kd = reinterpret_cast<uint2*>(Kc + (size_t)r * HID_C + tid * 4);
    uint2* vd = reinterpret_cast<uint2*>(Vc + (size_t)r * HID_C + tid * 4);
    if (j < nv) {
        const int src = cidx[b * S_LEN + j];
        const float4 kv = *reinterpret_cast<const float4*>(
            key + ((size_t)b * S_LEN + src) * HID_C + tid * 4);
        const float4 vv = *reinterpret_cast<const float4*>(
            value + ((size_t)b * S_LEN + src) * HID_C + tid * 4);
        uint2 kp, vp;
        kp.x = ((unsigned)f32_to_bf16_rn(kv.y) << 16) | f32_to_bf16_rn(kv.x);
        kp.y = ((unsigned)f32_to_bf16_rn(kv.w) << 16) | f32_to_bf16_rn(kv.z);
        vp.x = ((unsigned)f32_to_bf16_rn(vv.y) << 16) | f32_to_bf16_rn(vv.x);
        vp.y = ((unsigned)f32_to_bf16_rn(vv.w) << 16) | f32_to_bf16_rn(vv.z);
        *kd = kp; *vd = vp;
    } else {
        *kd = make_uint2(0u, 0u); *vd = make_uint2(0u, 0u);
    }
}

// ---------------------------------------------------------------------------
// MFMA GEMM with global_load_lds staging (all-bf16 sources).
// LDS linear [512 slots x 16B]; slot s holds data (r=s>>2, kq=(s&3)^((s>>3)&3));
// fragment read slot = r*4 + (kq ^ ((r>>1)&3))  -> 2-way banks (free).
// AMODE 3: single A (1 MFMA). AMODE 1: A hi/lo pair (2 MFMA, O-GEMM).
// OMODE 0: fp32 out/col bias. OMODE 1: bf16/col. OMODE 2: bf16/ROW bias.
// SKIP 1: skip m-stripes >= npads[batch]. SKIP 2: same on n.
// 128x128 tile, BK=32, 4 waves (2x2), 64x64/wave.
// ---------------------------------------------------------------------------
#define BM 128
#define BN 128

template <int OMODE, int AMODE, int SKIP>
__global__ __launch_bounds__(256) void gemm_bf16_glds(
    const ushort_t* __restrict__ Ab, const ushort_t* __restrict__ Abl,
    const ushort_t* __restrict__ Wb, const float* __restrict__ bias,
    const int* __restrict__ npads,
    float* __restrict__ outF, ushort_t* __restrict__ outB,
    int M, int N, int K, float oscale)
{
    __shared__ __align__(16) ushort_t Ah[128 * 32];
    __shared__ __align__(16) ushort_t Al[(AMODE == 1) ? 128 * 32 : 8];
    __shared__ __align__(16) ushort_t Bh[128 * 32];

    const int tid  = threadIdx.x;
    const int lane = tid & 63;
    const int bm = blockIdx.y * BM;
    const int bn = blockIdx.x * BN;

    if (SKIP == 1) { if ((bm & 2047) >= npads[bm >> 11]) return; }
    if (SKIP == 2) { if ((bn & 2047) >= npads[bn >> 11]) return; }

    const int wave = tid >> 6;
    const int wm = (wave >> 1) * 64;
    const int wn = (wave & 1) * 64;
    const int fr = lane & 15;
    const int kq = lane >> 4;

    // staging slots for this thread: s_i = i*256 + tid -> data (r, kq_d)
    int srow[2], skq[2];
#pragma unroll
    for (int i = 0; i < 2; ++i) {
        const int s = i * 256 + tid;
        srow[i] = s >> 2;
        skq[i] = (s & 3) ^ ((s >> 3) & 3);
    }
    const int wslot = tid & 192;   // wave slot base (uniform)

    f32x4 acc[4][4];
#pragma unroll
    for (int i = 0; i < 4; ++i)
#pragma unroll
        for (int j = 0; j < 4; ++j)
#pragma unroll
            for (int r = 0; r < 4; ++r) acc[i][j][r] = 0.f;

    for (int k0 = 0; k0 < K; k0 += 32) {
        __syncthreads();   // readers done with buffers
#pragma unroll
        for (int i = 0; i < 2; ++i) {
            const int sb = (i * 256 + wslot) * 8;
            const size_t ga = (size_t)(bm + srow[i]) * K + k0 + skq[i] * 8;
            const size_t gb = (size_t)(bn + srow[i]) * K + k0 + skq[i] * 8;
            gload16(Ab + ga, Ah + sb);
            if (AMODE == 1) gload16(Abl + ga, Al + sb);
            gload16(Wb + gb, Bh + sb);
        }
        __syncthreads();   // compiler drains vmcnt(0) -> tiles ready

        bf16x8 fah[4], fal[4], fbh[4];
#pragma unroll
        for (int mi = 0; mi < 4; ++mi) {
            const int rr = wm + mi * 16 + fr;
            const int sl = rr * 4 + (kq ^ ((rr >> 1) & 3));
            fah[mi] = *reinterpret_cast<const bf16x8*>(Ah + sl * 8);
            if (AMODE == 1) fal[mi] = *reinterpret_cast<const bf16x8*>(Al + sl * 8);
        }
#pragma unroll
        for (int ni = 0; ni < 4; ++ni) {
            const int rr = wn + ni * 16 + fr;
            const int sl = rr * 4 + (kq ^ ((rr >> 1) & 3));
            fbh[ni] = *reinterpret_cast<const bf16x8*>(Bh + sl * 8);
        }

#pragma unroll
        for (int mi = 0; mi < 4; ++mi)
#pragma unroll
            for (int ni = 0; ni < 4; ++ni) {
                acc[mi][ni] = __builtin_amdgcn_mfma_f32_16x16x32_bf16(
                    fah[mi], fbh[ni], acc[mi][ni], 0, 0, 0);
                if (AMODE == 1)
                    acc[mi][ni] = __builtin_amdgcn_mfma_f32_16x16x32_bf16(
                        fal[mi], fbh[ni], acc[mi][ni], 0, 0, 0);
            }
    }

    const int fq = lane >> 4;
    if (OMODE == 2) {
#pragma unroll
        for (int mi = 0; mi < 4; ++mi) {
#pragma unroll
            for (int r = 0; r < 4; ++r) {
                const int row = bm + wm + mi * 16 + fq * 4 + r;
                const float bvr = bias[row];
#pragma unroll
                for (int ni = 0; ni < 4; ++ni) {
                    const int col = bn + wn + ni * 16 + fr;
                    outB[(size_t)row * N + col] =
                        f32_to_bf16_rn((acc[mi][ni][r] + bvr) * oscale);
                }
            }
        }
    } else {
        float bv[4];
#pragma unroll
        for (int ni = 0; ni < 4; ++ni) bv[ni] = bias[bn + wn + ni * 16 + fr];
#pragma unroll
        for (int mi = 0; mi < 4; ++mi)
#pragma unroll
            for (int ni = 0; ni < 4; ++ni) {
                const size_t rowb = (size_t)(bm + wm + mi * 16 + fq * 4);
                const int col = bn + wn + ni * 16 + fr;
#pragma unroll
                for (int r = 0; r < 4; ++r) {
                    float v = (acc[mi][ni][r] + bv[ni]) * oscale;
                    if (OMODE == 0) outF[(rowb + r) * N + col] = v;
                    else            outB[(rowb + r) * N + col] = f32_to_bf16_rn(v);
                }
            }
    }
}

// ---------------------------------------------------------------------------
// Flash attention (unchanged from R11): 32x32 MFMA, swapped QK^T, in-register
// P via cvt_pk + permlane32_swap, compacted keys, XCD-affinity, defer-max.
// ---------------------------------------------------------------------------
#define QBLK 128
#define KVB  64
#define LDA  72

__global__ __launch_bounds__(256) void flash_attn_bf16(
    const ushort_t* __restrict__ Qb, const ushort_t* __restrict__ Kb,
    const ushort_t* __restrict__ Vtg, const float* __restrict__ maskb,
    const int* __restrict__ npads,
    ushort_t* __restrict__ Xhi, ushort_t* __restrict__ Xlo)
{
    __shared__ __align__(16) ushort_t Ks[KVB * LDA];
    __shared__ __align__(16) ushort_t Vt[HDIM * LDA];
    __shared__ float Xpose[QBLK];

    const int n  = blockIdx.x;
    const int bh = (n & 7) * 8 + ((n >> 3) & 7);
    const int qx = n >> 6;
    const int b  = bh >> 4;
    const int h  = bh & 15;
    const int q0 = qx * QBLK;

    const int tid  = threadIdx.x;
    const int lane = tid & 63;
    const int w    = tid >> 6;
    const int lq = lane & 31;
    const int lh = lane >> 5;

    const size_t bS = (size_t)b * S_LEN;
    const int hc = h * HDIM;
    const int npad = npads[b];

    bf16x8 qf[4];
#pragma unroll
    for (int s = 0; s < 4; ++s)
        qf[s] = *reinterpret_cast<const bf16x8*>(
            &Qb[(bS + q0 + w * 32 + lq) * HID_C + hc + s * 16 + lh * 8]);

    f32x16 OV[2];
#pragma unroll
    for (int dt = 0; dt < 2; ++dt)
#pragma unroll
        for (int r = 0; r < 16; ++r) OV[dt][r] = 0.f;
    float m_ = -1e30f, l_ = 0.f;

    const int sr  = tid >> 2;
    const int seg = tid & 3;
    const ushort_t* kbase = &Kb[(bS + sr) * HID_C + hc + seg * 16];
    const ushort_t* vbase = &Vtg[(size_t)(hc + sr) * (4 * S_LEN) + bS + seg * 16];

    {
        bf16x8 kv0 = *reinterpret_cast<const bf16x8*>(kbase);
        bf16x8 kv1 = *reinterpret_cast<const bf16x8*>(kbase + 8);
        bf16x8 vv0 = *reinterpret_cast<const bf16x8*>(vbase);
        bf16x8 vv1 = *reinterpret_cast<const bf16x8*>(vbase + 8);
        *reinterpret_cast<bf16x8*>(&Ks[sr * LDA + seg * 16])     = kv0;
        *reinterpret_cast<bf16x8*>(&Ks[sr * LDA + seg * 16 + 8]) = kv1;
        *reinterpret_cast<bf16x8*>(&Vt[sr * LDA + seg * 16])     = vv0;
        *reinterpret_cast<bf16x8*>(&Vt[sr * LDA + seg * 16 + 8]) = vv1;
        __syncthreads();
    }

    for (int t = 0; t < npad; t += KVB) {
        float4 mb[2][4];
#pragma unroll
        for (int kt = 0; kt < 2; ++kt)
#pragma unroll
            for (int g = 0; g < 4; ++g)
                mb[kt][g] = *reinterpret_cast<const float4*>(
                    &maskb[bS + t + kt * 32 + g * 8 + lh * 4]);

        f32x16 S[2];
#pragma unroll
        for (int kt = 0; kt < 2; ++kt)
#pragma unroll
            for (int r = 0; r < 16; ++r) S[kt][r] = 0.f;

        __builtin_amdgcn_s_setprio(1);
#pragma unroll
        for (int kt = 0; kt < 2; ++kt)
#pragma unroll
            for (int s = 0; s < 4; ++s) {
                bf16x8 kf = *reinterpret_cast<const bf16x8*>(
                    &Ks[(kt * 32 + lq) * LDA + s * 16 + lh * 8]);
                S[kt] = __builtin_amdgcn_mfma_f32_32x32x16_bf16(
                    kf, qf[s], S[kt], 0, 0, 0);
            }
        __builtin_amdgcn_s_setprio(0);

        const bool more = (t + KVB < npad);
        bf16x8 kv0n, kv1n, vv0n, vv1n;
        if (more) {
            const ushort_t* kp = kbase + (size_t)(t + KVB) * HID_C;
            const ushort_t* vp = vbase + (t + KVB);
            kv0n = *reinterpret_cast<const bf16x8*>(kp);
            kv1n = *reinterpret_cast<const bf16x8*>(kp + 8);
            vv0n = *reinterpret_cast<const bf16x8*>(vp);
            vv1n = *reinterpret_cast<const bf16x8*>(vp + 8);
        }

        float mx = -1e30f;
#pragma unroll
        for (int kt = 0; kt < 2; ++kt)
#pragma unroll
            for (int r = 0; r < 16; ++r) {
                float sv = S[kt][r] +
                    reinterpret_cast<const float*>(&mb[kt][r >> 2])[r & 3];
                S[kt][r] = sv;
                mx = fmaxf(mx, sv);
            }
        mx = fmaxf(mx, __shfl_xor(mx, 32));

        if (!__all(mx <= m_ + 8.f)) {
            float mn = fmaxf(m_, mx);
            float corr = exp2f(m_ - mn);
            m_ = mn; l_ *= corr;
            if (lh == 0) Xpose[w * 32 + lq] = corr;   // same-wave RAW
#pragma unroll
            for (int r = 0; r < 16; ++r) {
                float cq = Xpose[w * 32 + (r & 3) + 8 * (r >> 2) + 4 * lh];
                OV[0][r] *= cq;
                OV[1][r] *= cq;
            }
        }

        float ls = 0.f;
#pragma unroll
        for (int kt = 0; kt < 2; ++kt)
#pragma unroll
            for (int r = 0; r < 16; ++r) {
                float p = exp2f(S[kt][r] - m_);
                S[kt][r] = p;
                ls += p;
            }
        ls += __shfl_xor(ls, 32);
        l_ += ls;

        bf16x8 pa[4];
#pragma unroll
        for (int kt = 0; kt < 2; ++kt)
#pragma unroll
            for (int u = 0; u < 2; ++u) {
                const int bb = u * 8;
                unsigned int c0, c1, c2, c3;
                asm("v_cvt_pk_bf16_f32 %0, %1, %2"
                    : "=v"(c0) : "v"(S[kt][bb + 0]), "v"(S[kt][bb + 1]));
                asm("v_cvt_pk_bf16_f32 %0, %1, %2"
                    : "=v"(c1) : "v"(S[kt][bb + 2]), "v"(S[kt][bb + 3]));
                asm("v_cvt_pk_bf16_f32 %0, %1, %2"
                    : "=v"(c2) : "v"(S[kt][bb + 4]), "v"(S[kt][bb + 5]));
                asm("v_cvt_pk_bf16_f32 %0, %1, %2"
                    : "=v"(c3) : "v"(S[kt][bb + 6]), "v"(S[kt][bb + 7]));
                asm("v_permlane32_swap_b32 %0, %1" : "+v"(c0), "+v"(c2));
                asm("v_permlane32_swap_b32 %0, %1" : "+v"(c1), "+v"(c3));
                uint4 wv = make_uint4(c0, c1, c2, c3);
                pa[kt * 2 + u] = *reinterpret_cast<bf16x8*>(&wv);
            }

        __builtin_amdgcn_s_setprio(1);
#pragma unroll
        for (int dt = 0; dt < 2; ++dt)
#pragma unroll
            for (int f = 0; f < 4; ++f) {
                bf16x8 vf = *reinterpret_cast<const bf16x8*>(
                    &Vt[(dt * 32 + lq) * LDA + f * 16 + lh * 8]);
                OV[dt] = __builtin_amdgcn_mfma_f32_32x32x16_bf16(
                    pa[f], vf, OV[dt], 0, 0, 0);
            }
        __builtin_amdgcn_s_setprio(0);

        __syncthreads();
        if (more) {
            *reinterpret_cast<bf16x8*>(&Ks[sr * LDA + seg * 16])     = kv0n;
            *reinterpret_cast<bf16x8*>(&Ks[sr * LDA + seg * 16 + 8]) = kv1n;
            *reinterpret_cast<bf16x8*>(&Vt[sr * LDA + seg * 16])     = vv0n;
            *reinterpret_cast<bf16x8*>(&Vt[sr * LDA + seg * 16 + 8]) = vv1n;
            __syncthreads();
        }
    }

    if (lh == 0) Xpose[w * 32 + lq] = 1.f / l_;   // same-wave RAW
#pragma unroll
    for (int r = 0; r < 16; ++r) {
        const int qr = (r & 3) + 8 * (r >> 2) + 4 * lh;
        const float inv = Xpose[w * 32 + qr];
        const size_t row = bS + q0 + w * 32 + qr;
#pragma unroll
        for (int dt = 0; dt < 2; ++dt) {
            float v = OV[dt][r] * inv;
            unsigned int u = __float_as_uint(v);
            unsigned short hi = (unsigned short)(u >> 16);
            float res = v - __uint_as_float(u & 0xFFFF0000u);
            Xhi[row * HID_C + hc + dt * 32 + lq] = hi;
            Xlo[row * HID_C + hc + dt * 32 + lq] = f32_to_bf16_rn(res);
        }
    }
}

// ---------------------------------------------------------------------------
extern "C" void kernel_launch(void* const* d_in, const int* in_sizes, int n_in,
                              void* d_out, int out_size, void* d_ws, size_t ws_size,
                              hipStream_t stream) {
    const float* query = (const float*)d_in[0];
    const float* key   = (const float*)d_in[1];
    const float* value = (const float*)d_in[2];
    const int*   mask  = (const int*)d_in[3];
    const float* Wq = (const float*)d_in[4];
    const float* bq = (const float*)d_in[5];
    const float* Wk = (const float*)d_in[6];
    const float* bk = (const float*)d_in[7];
    const float* Wv = (const float*)d_in[8];
    const float* bv = (const float*)d_in[9];
    const float* Wo = (const float*)d_in[10];
    const float* bo = (const float*)d_in[11];
    float* out = (float*)d_out;

    const int B = 4, M = B * S_LEN;          // 8192
    const size_t seg = (size_t)M * HID_C;
    const size_t nw  = (size_t)HID_C * HID_C;

    ushort_t* Qb  = (ushort_t*)d_ws;         // 16MB each
    ushort_t* Kb  = Qb + seg;
    ushort_t* Vtg = Kb + seg;                // V^T: [1024 feat][8192 compact tok]
    ushort_t* Xhi = Vtg + seg;               // aliased: Kc before attn
    ushort_t* Xlo = Xhi + seg;               // aliased: Vc before attn
    ushort_t* Qbf = Xlo + seg;               // query bf16, 16MB
    float*    Mbc = (float*)(Qbf + seg);     // 32KB compact mask bias
    ushort_t* Wqb = (ushort_t*)(Mbc + 4 * S_LEN);
    ushort_t* Wkb = Wqb + nw;                // 2MB each
    ushort_t* Wob = Wkb + nw;
    ushort_t* Wvb = Wob + nw;
    int*      cidx   = (int*)(Wvb + nw);     // 32KB
    int*      nvalid = cidx + 4 * S_LEN;
    int*      npads  = nvalid + 4;           // total ~105MB

    ushort_t* Kc = Xhi;                      // compact bf16 key rows
    ushort_t* Vc = Xlo;                      // compact bf16 value rows

    {
        const unsigned total4 = (unsigned)((seg + 4 * nw) / 4);
        prep_conv<<<dim3((total4 + 255) / 256), 256, 0, stream>>>(
            query, Wq, Wk, Wo, Wv, Qbf, Wqb, Wkb, Wob, Wvb);
    }
    scan_mask<<<dim3(4), 64, 0, stream>>>(mask, cidx, nvalid, npads);
    gather_kv<<<dim3(M), 256, 0, stream>>>(key, value, cidx, nvalid, Kc, Vc, Mbc);

    const float SC2 = 0.125f * LOG2E;
    dim3 gg(HID_C / BN, M / BM);             // (8, 64)
    gemm_bf16_glds<1, 3, 0><<<gg, 256, 0, stream>>>(
        Qbf, nullptr, Wqb, bq, npads, nullptr, Qb, M, HID_C, HID_C, SC2);
    gemm_bf16_glds<1, 3, 1><<<gg, 256, 0, stream>>>(
        Kc, nullptr, Wkb, bk, npads, nullptr, Kb, M, HID_C, HID_C, 1.f);
    dim3 gv(M / BN, HID_C / BM);             // (64, 8)
    gemm_bf16_glds<2, 3, 2><<<gv, 256, 0, stream>>>(
        Wvb, nullptr, Vc, bv, npads, nullptr, Vtg, HID_C, M, HID_C, 1.f);

    flash_attn_bf16<<<dim3((S_LEN / QBLK) * B * NHEADS), 256, 0, stream>>>(
        Qb, Kb, Vtg, Mbc, npads, Xhi, Xlo);

    gemm_bf16_glds<0, 1, 0><<<gg, 256, 0, stream>>>(
        Xhi, Xlo, Wob, bo, npads, out, nullptr, M, HID_C, HID_C, 1.f);
}

// Round 15
// 214.552 us; speedup vs baseline: 2.1898x; 1.1362x over previous
//
#include <hip/hip_runtime.h>
#include <cstddef>
#include <math.h>

#define S_LEN  2048
#define HID_C  1024
#define NHEADS 16
#define HDIM   64

typedef __attribute__((ext_vector_type(8))) short bf16x8;
typedef __attribute__((ext_vector_type(4))) float f32x4;
typedef __attribute__((ext_vector_type(16))) float f32x16;
typedef unsigned short ushort_t;

#define LOG2E 1.44269504088896f

__device__ __forceinline__ unsigned short f32_to_bf16_rn(float f) {
    unsigned int u = __float_as_uint(f);
    return (unsigned short)((u + 0x8000u) >> 16);
}

// direct global->LDS 16B copy (lds dest = wave-uniform base + lane*16)
__device__ __forceinline__ void gload16(const ushort_t* g, ushort_t* l) {
    __builtin_amdgcn_global_load_lds(
        (const __attribute__((address_space(1))) void*)g,
        (__attribute__((address_space(3))) void*)l, 16, 0, 0);
}

// balanced tree reductions over f32x16 (depth 5; max3-fusable)
__device__ __forceinline__ float tmax16(const f32x16& v) {
    float a0 = fmaxf(v[0], v[1]),   a1 = fmaxf(v[2], v[3]);
    float a2 = fmaxf(v[4], v[5]),   a3 = fmaxf(v[6], v[7]);
    float a4 = fmaxf(v[8], v[9]),   a5 = fmaxf(v[10], v[11]);
    float a6 = fmaxf(v[12], v[13]), a7 = fmaxf(v[14], v[15]);
    float b0 = fmaxf(a0, a1), b1 = fmaxf(a2, a3);
    float b2 = fmaxf(a4, a5), b3 = fmaxf(a6, a7);
    return fmaxf(fmaxf(b0, b1), fmaxf(b2, b3));
}
__device__ __forceinline__ float tsum16(const f32x16& v) {
    float a0 = v[0] + v[1],   a1 = v[2] + v[3];
    float a2 = v[4] + v[5],   a3 = v[6] + v[7];
    float a4 = v[8] + v[9],   a5 = v[10] + v[11];
    float a6 = v[12] + v[13], a7 = v[14] + v[15];
    float b0 = a0 + a1, b1 = a2 + a3, b2 = a4 + a5, b3 = a6 + a7;
    return (b0 + b1) + (b2 + b3);
}

// ---------------------------------------------------------------------------
// scan: order-preserving compaction of valid key indices per batch.
// ---------------------------------------------------------------------------
__global__ void scan_mask(const int* __restrict__ mask, int* __restrict__ cidx,
                          int* __restrict__ nvalid, int* __restrict__ npads) {
    const int b = blockIdx.x;
    const int lane = threadIdx.x;           // blockDim.x == 64
    int base = 0;
    for (int i = 0; i < S_LEN / 64; ++i) {
        const int s = i * 64 + lane;
        const int v = mask[b * S_LEN + s];
        const unsigned long long bal = __ballot(v != 0);
        const int pre = __popcll(bal & ((1ull << lane) - 1ull));
        if (v) cidx[b * S_LEN + base + pre] = s;
        base += (int)__popcll(bal);
    }
    if (lane == 0) { nvalid[b] = base; npads[b] = (base + 63) & ~63; }
}

// ---------------------------------------------------------------------------
// fused prep + gather:
//  blocks [0, 12288):  fp32->bf16 convert of query + Wq/Wk/Wo/Wv (4/thread)
//  blocks [12288, 20480): compact-gather bf16 key/value rows + mask bias
// ---------------------------------------------------------------------------
#define CONVB 12288

__global__ void prep_gather(
    const float* __restrict__ query,
    const float* __restrict__ Wq, const float* __restrict__ Wk,
    const float* __restrict__ Wo, const float* __restrict__ Wv,
    const float* __restrict__ key, const float* __restrict__ value,
    const int* __restrict__ cidx, const int* __restrict__ nvalid,
    ushort_t* __restrict__ Qbf, ushort_t* __restrict__ Wqb,
    ushort_t* __restrict__ Wkb, ushort_t* __restrict__ Wob,
    ushort_t* __restrict__ Wvb,
    ushort_t* __restrict__ Kc, ushort_t* __restrict__ Vc,
    float* __restrict__ Mbc)
{
    if (blockIdx.x < CONVB) {
        const unsigned SEG = 4u * S_LEN * HID_C;
        const unsigned NW = HID_C * HID_C;
        unsigned i = (blockIdx.x * 256u + threadIdx.x) * 4u;
        const float* src; ushort_t* dst;
        if (i < SEG) { src = query; dst = Qbf; }
        else {
            i -= SEG;
            if (i < NW) { src = Wq; dst = Wqb; }
            else { i -= NW;
                if (i < NW) { src = Wk; dst = Wkb; }
                else { i -= NW;
                    if (i < NW) { src = Wo; dst = Wob; }
                    else { i -= NW; if (i >= NW) return; src = Wv; dst = Wvb; }
                }
            }
        }
        float4 v = *reinterpret_cast<const float4*>(src + i);
        uint2 p;
        p.x = ((unsigned)f32_to_bf16_rn(v.y) << 16) | f32_to_bf16_rn(v.x);
        p.y = ((unsigned)f32_to_bf16_rn(v.w) << 16) | f32_to_bf16_rn(v.z);
        *reinterpret_cast<uint2*>(dst + i) = p;
    } else {
        const int r = blockIdx.x - CONVB;       // 0..8191 compact row
        const int b = r >> 11, j = r & 2047;
        const int tid = threadIdx.x;
        const int nv = nvalid[b];
        if (tid == 0) Mbc[r] = (j < nv) ? 0.f : -1e30f;
        const int np128 = (nv + 127) & ~127;
        if (j >= np128) return;
        uint2* kd = reinterpret_cast<uint2*>(Kc + (size_t)r * HID_C + tid * 4);
        uint2* vd = reinterpret_cast<uint2*>(Vc + (size_t)r * HID_C + tid * 4);
        if (j < nv) {
            const int src = cidx[b * S_LEN + j];
            const float4 kv = *reinterpret_cast<const float4*>(
                key + ((size_t)b * S_LEN + src) * HID_C + tid * 4);
            const float4 vv = *reinterpret_cast<const float4*>(
                value + ((size_t)b * S_LEN + src) * HID_C + tid * 4);
            uint2 kp, vp;
            kp.x = ((unsigned)f32_to_bf16_rn(kv.y) << 16) | f32_to_bf16_rn(kv.x);
            kp.y = ((unsigned)f32_to_bf16_rn(kv.w) << 16) | f32_to_bf16_rn(kv.z);
            vp.x = ((unsigned)f32_to_bf16_rn(vv.y) << 16) | f32_to_bf16_rn(vv.x);
            vp.y = ((unsigned)f32_to_bf16_rn(vv.w) << 16) | f32_to_bf16_rn(vv.z);
            *kd = kp; *vd = vp;
        } else {
            *kd = make_uint2(0u, 0u); *vd = make_uint2(0u, 0u);
        }
    }
}

// ---------------------------------------------------------------------------
// shared GEMM core (bf16 A & W, global_load_lds staging, 1 MFMA/pair).
// LDS linear [512 slots x 16B]; slot s holds data (r=s>>2, kq=(s&3)^((s>>3)&3));
// fragment read slot = r*4 + (kq ^ ((r>>1)&3))  -> near-uniform banks.
// rowBias=false: out[row][col] += bias[col]; true: += bias[row] (V^T GEMM).
// ---------------------------------------------------------------------------
__device__ __forceinline__ void gemm_core(
    const ushort_t* __restrict__ Ab, const ushort_t* __restrict__ Wb,
    const float* __restrict__ bias, ushort_t* __restrict__ outB,
    int bm, int bn, int N, int K, float oscale, bool rowBias,
    ushort_t* Ah, ushort_t* Bh)
{
    const int tid  = threadIdx.x;
    const int lane = tid & 63;
    const int wave = tid >> 6;
    const int wm = (wave >> 1) * 64;
    const int wn = (wave & 1) * 64;
    const int fr = lane & 15;
    const int kq = lane >> 4;

    int srow[2], skq[2];
#pragma unroll
    for (int i = 0; i < 2; ++i) {
        const int s = i * 256 + tid;
        srow[i] = s >> 2;
        skq[i] = (s & 3) ^ ((s >> 3) & 3);
    }
    const int wslot = tid & 192;

    f32x4 acc[4][4];
#pragma unroll
    for (int i = 0; i < 4; ++i)
#pragma unroll
        for (int j = 0; j < 4; ++j)
#pragma unroll
            for (int r = 0; r < 4; ++r) acc[i][j][r] = 0.f;

    for (int k0 = 0; k0 < K; k0 += 32) {
        __syncthreads();
#pragma unroll
        for (int i = 0; i < 2; ++i) {
            const int sb = (i * 256 + wslot) * 8;
            gload16(Ab + (size_t)(bm + srow[i]) * K + k0 + skq[i] * 8, Ah + sb);
            gload16(Wb + (size_t)(bn + srow[i]) * K + k0 + skq[i] * 8, Bh + sb);
        }
        __syncthreads();

        bf16x8 fah[4], fbh[4];
#pragma unroll
        for (int mi = 0; mi < 4; ++mi) {
            const int rr = wm + mi * 16 + fr;
            fah[mi] = *reinterpret_cast<const bf16x8*>(
                Ah + (rr * 4 + (kq ^ ((rr >> 1) & 3))) * 8);
        }
#pragma unroll
        for (int ni = 0; ni < 4; ++ni) {
            const int rr = wn + ni * 16 + fr;
            fbh[ni] = *reinterpret_cast<const bf16x8*>(
                Bh + (rr * 4 + (kq ^ ((rr >> 1) & 3))) * 8);
        }

#pragma unroll
        for (int mi = 0; mi < 4; ++mi)
#pragma unroll
            for (int ni = 0; ni < 4; ++ni)
                acc[mi][ni] = __builtin_amdgcn_mfma_f32_16x16x32_bf16(
                    fah[mi], fbh[ni], acc[mi][ni], 0, 0, 0);
    }

    const int fq = lane >> 4;
    if (rowBias) {
#pragma unroll
        for (int mi = 0; mi < 4; ++mi)
#pragma unroll
            for (int r = 0; r < 4; ++r) {
                const int row = bm + wm + mi * 16 + fq * 4 + r;
                const float bvr = bias[row];
#pragma unroll
                for (int ni = 0; ni < 4; ++ni)
                    outB[(size_t)row * N + bn + wn + ni * 16 + fr] =
                        f32_to_bf16_rn((acc[mi][ni][r] + bvr) * oscale);
            }
    } else {
        float bv[4];
#pragma unroll
        for (int ni = 0; ni < 4; ++ni) bv[ni] = bias[bn + wn + ni * 16 + fr];
#pragma unroll
        for (int mi = 0; mi < 4; ++mi)
#pragma unroll
            for (int ni = 0; ni < 4; ++ni) {
                const size_t rowb = (size_t)(bm + wm + mi * 16 + fq * 4);
                const int col = bn + wn + ni * 16 + fr;
#pragma unroll
                for (int r = 0; r < 4; ++r)
                    outB[(rowb + r) * N + col] =
                        f32_to_bf16_rn((acc[mi][ni][r] + bv[ni]) * oscale);
            }
    }
}

// ---------------------------------------------------------------------------
// fused Q/K/V^T projections: one launch, blocks co-scheduled.
//  [0,512): Q = query @ Wq^T (scaled); [512,1024): K (skip-striped);
//  [1024,1536): V^T = Wv @ Vc^T (row bias, token stripes skip-striped).
// ---------------------------------------------------------------------------
__global__ __launch_bounds__(256) void proj_fused(
    const ushort_t* __restrict__ Qbf, const ushort_t* __restrict__ Kc,
    const ushort_t* __restrict__ Wvb, const ushort_t* __restrict__ Vc,
    const ushort_t* __restrict__ Wqb, const ushort_t* __restrict__ Wkb,
    const float* __restrict__ bq, const float* __restrict__ bk,
    const float* __restrict__ bv, const int* __restrict__ npads,
    ushort_t* __restrict__ Qb, ushort_t* __restrict__ Kb,
    ushort_t* __restrict__ Vtg, float sc2)
{
    __shared__ __align__(16) ushort_t Ah[128 * 32];
    __shared__ __align__(16) ushort_t Bh[128 * 32];

    int id = blockIdx.x;
    if (id < 512) {
        gemm_core(Qbf, Wqb, bq, Qb, (id >> 3) * 128, (id & 7) * 128,
                  HID_C, HID_C, sc2, false, Ah, Bh);
    } else if (id < 1024) {
        id -= 512;
        const int bm = (id >> 3) * 128;
        if ((bm & 2047) >= npads[bm >> 11]) return;
        gemm_core(Kc, Wkb, bk, Kb, bm, (id & 7) * 128,
                  HID_C, HID_C, 1.f, false, Ah, Bh);
    } else {
        id -= 1024;
        const int bn = (id & 63) * 128;
        if ((bn & 2047) >= npads[bn >> 11]) return;
        gemm_core(Wvb, Vc, bv, Vtg, (id >> 6) * 128, bn,
                  4 * S_LEN, HID_C, 1.f, true, Ah, Bh);
    }
}

// ---------------------------------------------------------------------------
// O-GEMM: fp32 out, split-A (hi/lo, 2 MFMA), gload_lds staging.
// ---------------------------------------------------------------------------
__global__ __launch_bounds__(256) void gemm_out(
    const ushort_t* __restrict__ Xhi, const ushort_t* __restrict__ Xlo,
    const ushort_t* __restrict__ Wb, const float* __restrict__ bias,
    float* __restrict__ outF, int M, int N, int K)
{
    __shared__ __align__(16) ushort_t Ah[128 * 32];
    __shared__ __align__(16) ushort_t Al[128 * 32];
    __shared__ __align__(16) ushort_t Bh[128 * 32];

    const int tid  = threadIdx.x;
    const int lane = tid & 63;
    const int wave = tid >> 6;
    const int bm = blockIdx.y * 128;
    const int bn = blockIdx.x * 128;
    const int wm = (wave >> 1) * 64;
    const int wn = (wave & 1) * 64;
    const int fr = lane & 15;
    const int kq = lane >> 4;

    int srow[2], skq[2];
#pragma unroll
    for (int i = 0; i < 2; ++i) {
        const int s = i * 256 + tid;
        srow[i] = s >> 2;
        skq[i] = (s & 3) ^ ((s >> 3) & 3);
    }
    const int wslot = tid & 192;

    f32x4 acc[4][4];
#pragma unroll
    for (int i = 0; i < 4; ++i)
#pragma unroll
        for (int j = 0; j < 4; ++j)
#pragma unroll
            for (int r = 0; r < 4; ++r) acc[i][j][r] = 0.f;

    for (int k0 = 0; k0 < K; k0 += 32) {
        __syncthreads();
#pragma unroll
        for (int i = 0; i < 2; ++i) {
            const int sb = (i * 256 + wslot) * 8;
            const size_t ga = (size_t)(bm + srow[i]) * K + k0 + skq[i] * 8;
            gload16(Xhi + ga, Ah + sb);
            gload16(Xlo + ga, Al + sb);
            gload16(Wb + (size_t)(bn + srow[i]) * K + k0 + skq[i] * 8, Bh + sb);
        }
        __syncthreads();

        bf16x8 fah[4], fal[4], fbh[4];
#pragma unroll
        for (int mi = 0; mi < 4; ++mi) {
            const int rr = wm + mi * 16 + fr;
            const int sl = (rr * 4 + (kq ^ ((rr >> 1) & 3))) * 8;
            fah[mi] = *reinterpret_cast<const bf16x8*>(Ah + sl);
            fal[mi] = *reinterpret_cast<const bf16x8*>(Al + sl);
        }
#pragma unroll
        for (int ni = 0; ni < 4; ++ni) {
            const int rr = wn + ni * 16 + fr;
            fbh[ni] = *reinterpret_cast<const bf16x8*>(
                Bh + (rr * 4 + (kq ^ ((rr >> 1) & 3))) * 8);
        }

#pragma unroll
        for (int mi = 0; mi < 4; ++mi)
#pragma unroll
            for (int ni = 0; ni < 4; ++ni) {
                acc[mi][ni] = __builtin_amdgcn_mfma_f32_16x16x32_bf16(
                    fah[mi], fbh[ni], acc[mi][ni], 0, 0, 0);
                acc[mi][ni] = __builtin_amdgcn_mfma_f32_16x16x32_bf16(
                    fal[mi], fbh[ni], acc[mi][ni], 0, 0, 0);
            }
    }

    const int fq = lane >> 4;
    float bv[4];
#pragma unroll
    for (int ni = 0; ni < 4; ++ni) bv[ni] = bias[bn + wn + ni * 16 + fr];
#pragma unroll
    for (int mi = 0; mi < 4; ++mi)
#pragma unroll
        for (int ni = 0; ni < 4; ++ni) {
            const size_t rowb = (size_t)(bm + wm + mi * 16 + fq * 4);
            const int col = bn + wn + ni * 16 + fr;
#pragma unroll
            for (int r = 0; r < 4; ++r)
                outF[(rowb + r) * N + col] = acc[mi][ni][r] + bv[ni];
        }
}

// ---------------------------------------------------------------------------
// Flash attention: 32x32 MFMA, swapped QK^T, in-register P (cvt_pk+permlane),
// compacted keys (mask applied only in the final tile), tree reductions,
// XCD-affinity grid, defer-max, T14 reg-prefetch.
// ---------------------------------------------------------------------------
#define QBLK 128
#define KVB  64
#define LDA  72

__global__ __launch_bounds__(256) void flash_attn_bf16(
    const ushort_t* __restrict__ Qb, const ushort_t* __restrict__ Kb,
    const ushort_t* __restrict__ Vtg, const float* __restrict__ maskb,
    const int* __restrict__ npads,
    ushort_t* __restrict__ Xhi, ushort_t* __restrict__ Xlo)
{
    __shared__ __align__(16) ushort_t Ks[KVB * LDA];
    __shared__ __align__(16) ushort_t Vt[HDIM * LDA];
    __shared__ float Xpose[QBLK];

    const int n  = blockIdx.x;
    const int bh = (n & 7) * 8 + ((n >> 3) & 7);
    const int qx = n >> 6;
    const int b  = bh >> 4;
    const int h  = bh & 15;
    const int q0 = qx * QBLK;

    const int tid  = threadIdx.x;
    const int lane = tid & 63;
    const int w    = tid >> 6;
    const int lq = lane & 31;
    const int lh = lane >> 5;

    const size_t bS = (size_t)b * S_LEN;
    const int hc = h * HDIM;
    const int npad = npads[b];

    bf16x8 qf[4];
#pragma unroll
    for (int s = 0; s < 4; ++s)
        qf[s] = *reinterpret_cast<const bf16x8*>(
            &Qb[(bS + q0 + w * 32 + lq) * HID_C + hc + s * 16 + lh * 8]);

    f32x16 OV[2];
#pragma unroll
    for (int dt = 0; dt < 2; ++dt)
#pragma unroll
        for (int r = 0; r < 16; ++r) OV[dt][r] = 0.f;
    float m_ = -1e30f, l_ = 0.f;

    const int sr  = tid >> 2;
    const int seg = tid & 3;
    const ushort_t* kbase = &Kb[(bS + sr) * HID_C + hc + seg * 16];
    const ushort_t* vbase = &Vtg[(size_t)(hc + sr) * (4 * S_LEN) + bS + seg * 16];

    {
        bf16x8 kv0 = *reinterpret_cast<const bf16x8*>(kbase);
        bf16x8 kv1 = *reinterpret_cast<const bf16x8*>(kbase + 8);
        bf16x8 vv0 = *reinterpret_cast<const bf16x8*>(vbase);
        bf16x8 vv1 = *reinterpret_cast<const bf16x8*>(vbase + 8);
        *reinterpret_cast<bf16x8*>(&Ks[sr * LDA + seg * 16])     = kv0;
        *reinterpret_cast<bf16x8*>(&Ks[sr * LDA + seg * 16 + 8]) = kv1;
        *reinterpret_cast<bf16x8*>(&Vt[sr * LDA + seg * 16])     = vv0;
        *reinterpret_cast<bf16x8*>(&Vt[sr * LDA + seg * 16 + 8]) = vv1;
        __syncthreads();
    }

    for (int t = 0; t < npad; t += KVB) {
        // ---- QK^T (swapped, 32x32x16) ----
        f32x16 S[2];
#pragma unroll
        for (int kt = 0; kt < 2; ++kt)
#pragma unroll
            for (int r = 0; r < 16; ++r) S[kt][r] = 0.f;

        __builtin_amdgcn_s_setprio(1);
#pragma unroll
        for (int kt = 0; kt < 2; ++kt)
#pragma unroll
            for (int s = 0; s < 4; ++s) {
                bf16x8 kf = *reinterpret_cast<const bf16x8*>(
                    &Ks[(kt * 32 + lq) * LDA + s * 16 + lh * 8]);
                S[kt] = __builtin_amdgcn_mfma_f32_32x32x16_bf16(
                    kf, qf[s], S[kt], 0, 0, 0);
            }
        __builtin_amdgcn_s_setprio(0);

        // ---- T14: issue next-tile K/V loads ----
        const bool more = (t + KVB < npad);
        bf16x8 kv0n, kv1n, vv0n, vv1n;
        if (more) {
            const ushort_t* kp = kbase + (size_t)(t + KVB) * HID_C;
            const ushort_t* vp = vbase + (t + KVB);
            kv0n = *reinterpret_cast<const bf16x8*>(kp);
            kv1n = *reinterpret_cast<const bf16x8*>(kp + 8);
            vv0n = *reinterpret_cast<const bf16x8*>(vp);
            vv1n = *reinterpret_cast<const bf16x8*>(vp + 8);
        }

        // ---- mask bias: only the FINAL tile can contain padded keys ----
        if (!more) {
#pragma unroll
            for (int kt = 0; kt < 2; ++kt)
#pragma unroll
                for (int g = 0; g < 4; ++g) {
                    float4 mv = *reinterpret_cast<const float4*>(
                        &maskb[bS + t + kt * 32 + g * 8 + lh * 4]);
#pragma unroll
                    for (int e = 0; e < 4; ++e)
                        S[kt][g * 4 + e] += reinterpret_cast<const float*>(&mv)[e];
                }
        }

        // ---- tree row-max (one q per lane) ----
        float mx = fmaxf(tmax16(S[0]), tmax16(S[1]));
        mx = fmaxf(mx, __shfl_xor(mx, 32));

        // ---- defer-max (rare rescale) ----
        if (!__all(mx <= m_ + 8.f)) {
            float mn = fmaxf(m_, mx);
            float corr = exp2f(m_ - mn);
            m_ = mn; l_ *= corr;
            if (lh == 0) Xpose[w * 32 + lq] = corr;   // same-wave RAW
#pragma unroll
            for (int r = 0; r < 16; ++r) {
                float cq = Xpose[w * 32 + (r & 3) + 8 * (r >> 2) + 4 * lh];
                OV[0][r] *= cq;
                OV[1][r] *= cq;
            }
        }

        // ---- P = exp2(S - m), tree row-sum ----
#pragma unroll
        for (int kt = 0; kt < 2; ++kt)
#pragma unroll
            for (int r = 0; r < 16; ++r) S[kt][r] = exp2f(S[kt][r] - m_);
        float ls = tsum16(S[0]) + tsum16(S[1]);
        ls += __shfl_xor(ls, 32);
        l_ += ls;

        // ---- P -> PV A-frags in registers (cvt_pk + permlane32_swap) ----
        bf16x8 pa[4];
#pragma unroll
        for (int kt = 0; kt < 2; ++kt)
#pragma unroll
            for (int u = 0; u < 2; ++u) {
                const int bb = u * 8;
                unsigned int c0, c1, c2, c3;
                asm("v_cvt_pk_bf16_f32 %0, %1, %2"
                    : "=v"(c0) : "v"(S[kt][bb + 0]), "v"(S[kt][bb + 1]));
                asm("v_cvt_pk_bf16_f32 %0, %1, %2"
                    : "=v"(c1) : "v"(S[kt][bb + 2]), "v"(S[kt][bb + 3]));
                asm("v_cvt_pk_bf16_f32 %0, %1, %2"
                    : "=v"(c2) : "v"(S[kt][bb + 4]), "v"(S[kt][bb + 5]));
                asm("v_cvt_pk_bf16_f32 %0, %1, %2"
                    : "=v"(c3) : "v"(S[kt][bb + 6]), "v"(S[kt][bb + 7]));
                asm("v_permlane32_swap_b32 %0, %1" : "+v"(c0), "+v"(c2));
                asm("v_permlane32_swap_b32 %0, %1" : "+v"(c1), "+v"(c3));
                uint4 wv = make_uint4(c0, c1, c2, c3);
                pa[kt * 2 + u] = *reinterpret_cast<bf16x8*>(&wv);
            }

        // ---- PV (32x32x16) ----
        __builtin_amdgcn_s_setprio(1);
#pragma unroll
        for (int dt = 0; dt < 2; ++dt)
#pragma unroll
            for (int f = 0; f < 4; ++f) {
                bf16x8 vf = *reinterpret_cast<const bf16x8*>(
                    &Vt[(dt * 32 + lq) * LDA + f * 16 + lh * 8]);
                OV[dt] = __builtin_amdgcn_mfma_f32_32x32x16_bf16(
                    pa[f], vf, OV[dt], 0, 0, 0);
            }
        __builtin_amdgcn_s_setprio(0);

        // ---- stage next tile ----
        __syncthreads();
        if (more) {
            *reinterpret_cast<bf16x8*>(&Ks[sr * LDA + seg * 16])     = kv0n;
            *reinterpret_cast<bf16x8*>(&Ks[sr * LDA + seg * 16 + 8]) = kv1n;
            *reinterpret_cast<bf16x8*>(&Vt[sr * LDA + seg * 16])     = vv0n;
            *reinterpret_cast<bf16x8*>(&Vt[sr * LDA + seg * 16 + 8]) = vv1n;
            __syncthreads();
        }
    }

    // ---- epilogue: x = OV/l, pre-split hi/lo bf16 ----
    if (lh == 0) Xpose[w * 32 + lq] = 1.f / l_;   // same-wave RAW
#pragma unroll
    for (int r = 0; r < 16; ++r) {
        const int qr = (r & 3) + 8 * (r >> 2) + 4 * lh;
        const float inv = Xpose[w * 32 + qr];
        const size_t row = bS + q0 + w * 32 + qr;
#pragma unroll
        for (int dt = 0; dt < 2; ++dt) {
            float v = OV[dt][r] * inv;
            unsigned int u = __float_as_uint(v);
            unsigned short hi = (unsigned short)(u >> 16);
            float res = v - __uint_as_float(u & 0xFFFF0000u);
            Xhi[row * HID_C + hc + dt * 32 + lq] = hi;
            Xlo[row * HID_C + hc + dt * 32 + lq] = f32_to_bf16_rn(res);
        }
    }
}

// ---------------------------------------------------------------------------
extern "C" void kernel_launch(void* const* d_in, const int* in_sizes, int n_in,
                              void* d_out, int out_size, void* d_ws, size_t ws_size,
                              hipStream_t stream) {
    const float* query = (const float*)d_in[0];
    const float* key   = (const float*)d_in[1];
    const float* value = (const float*)d_in[2];
    const int*   mask  = (const int*)d_in[3];
    const float* Wq = (const float*)d_in[4];
    const float* bq = (const float*)d_in[5];
    const float* Wk = (const float*)d_in[6];
    const float* bk = (const float*)d_in[7];
    const float* Wv = (const float*)d_in[8];
    const float* bv = (const float*)d_in[9];
    const float* Wo = (const float*)d_in[10];
    const float* bo = (const float*)d_in[11];
    float* out = (float*)d_out;

    const int B = 4, M = B * S_LEN;          // 8192
    const size_t seg = (size_t)M * HID_C;
    const size_t nw  = (size_t)HID_C * HID_C;

    ushort_t* Qb  = (ushort_t*)d_ws;         // 16MB each
    ushort_t* Kb  = Qb + seg;
    ushort_t* Vtg = Kb + seg;                // V^T: [1024 feat][8192 compact tok]
    ushort_t* Xhi = Vtg + seg;               // aliased: Kc before attn
    ushort_t* Xlo = Xhi + seg;               // aliased: Vc before attn
    ushort_t* Qbf = Xlo + seg;               // query bf16
    float*    Mbc = (float*)(Qbf + seg);     // 32KB compact mask bias
    ushort_t* Wqb = (ushort_t*)(Mbc + 4 * S_LEN);
    ushort_t* Wkb = Wqb + nw;                // 2MB each
    ushort_t* Wob = Wkb + nw;
    ushort_t* Wvb = Wob + nw;
    int*      cidx   = (int*)(Wvb + nw);     // 32KB
    int*      nvalid = cidx + 4 * S_LEN;
    int*      npads  = nvalid + 4;           // total ~105MB

    ushort_t* Kc = Xhi;                      // compact bf16 key rows
    ushort_t* Vc = Xlo;                      // compact bf16 value rows

    scan_mask<<<dim3(4), 64, 0, stream>>>(mask, cidx, nvalid, npads);
    prep_gather<<<dim3(CONVB + M), 256, 0, stream>>>(
        query, Wq, Wk, Wo, Wv, key, value, cidx, nvalid,
        Qbf, Wqb, Wkb, Wob, Wvb, Kc, Vc, Mbc);

    const float SC2 = 0.125f * LOG2E;
    proj_fused<<<dim3(1536), 256, 0, stream>>>(
        Qbf, Kc, Wvb, Vc, Wqb, Wkb, bq, bk, bv, npads, Qb, Kb, Vtg, SC2);

    flash_attn_bf16<<<dim3((S_LEN / QBLK) * B * NHEADS), 256, 0, stream>>>(
        Qb, Kb, Vtg, Mbc, npads, Xhi, Xlo);

    gemm_out<<<dim3(HID_C / 128, M / 128), 256, 0, stream>>>(
        Xhi, Xlo, Wob, bo, out, M, HID_C, HID_C);
}